// Round 12
// baseline (4596.251 us; speedup 1.0000x reference)
//
#include <hip/hip_runtime.h>

constexpr int B  = 64;
constexpr int T  = 121;
constexpr int E  = 300;
constexpr int Ep = 320;    // E padded to K-chunk multiple
constexpr int H  = 256;
constexpr int G4 = 1024;   // 4*H
constexpr int D  = 512;    // 2*H
constexpr int NH = 3;
constexpr int BT = B * T;  // 7744
constexpr int Mp = 7808;   // 61*128, M padded for 128-row tiles

using short8 = __attribute__((ext_vector_type(8))) short;
using f32x4  = __attribute__((ext_vector_type(4))) float;

__device__ __forceinline__ float sigmoidf(float x) { return 1.0f / (1.0f + __expf(-x)); }
__device__ __forceinline__ float tanhf_fast(float x) {
  float e = __expf(2.0f * x);
  return 1.0f - 2.0f / (e + 1.0f);
}
__device__ __forceinline__ unsigned bf16rne(float x) {
  unsigned u = __float_as_uint(x);
  return (u + 0x7fffu + ((u >> 16) & 1u)) >> 16;
}
__device__ __forceinline__ float bf_lo(unsigned u) { return __uint_as_float(u << 16); }
__device__ __forceinline__ float bf_hi(unsigned u) { return __uint_as_float(u & 0xffff0000u); }
__device__ __forceinline__ float bfu(unsigned short u) { return __uint_as_float(((unsigned)u) << 16); }

// ---------------- weight packing ----------------
// LSTM: bf16 pair-packed, uint4-grouped (round-4 verified)
__global__ void k_pack_lstm(const float* __restrict__ Wh,
                            uint4* __restrict__ PAQ, uint4* __restrict__ PBQ) {
  int idx = blockIdx.x * 256 + threadIdx.x;   // over (H/4)*256 = 16384
  int k4 = idx >> 8, j = idx & 255;
  int k = 4 * k4;
  uint4 a, bq;
  const float* r0 = Wh + (size_t)(k + 0) * G4;
  const float* r1 = Wh + (size_t)(k + 1) * G4;
  const float* r2 = Wh + (size_t)(k + 2) * G4;
  const float* r3 = Wh + (size_t)(k + 3) * G4;
  a.x  = bf16rne(r0[j]) | (bf16rne(r0[j + 256]) << 16);
  a.y  = bf16rne(r1[j]) | (bf16rne(r1[j + 256]) << 16);
  a.z  = bf16rne(r2[j]) | (bf16rne(r2[j + 256]) << 16);
  a.w  = bf16rne(r3[j]) | (bf16rne(r3[j + 256]) << 16);
  bq.x = bf16rne(r0[j + 512]) | (bf16rne(r0[j + 768]) << 16);
  bq.y = bf16rne(r1[j + 512]) | (bf16rne(r1[j + 768]) << 16);
  bq.z = bf16rne(r2[j + 512]) | (bf16rne(r2[j + 768]) << 16);
  bq.w = bf16rne(r3[j + 512]) | (bf16rne(r3[j + 768]) << 16);
  PAQ[idx] = a;
  PBQ[idx] = bq;
}

// generic B^T bf16 pack with zero padding: WT[n*Kpad + k] = bf16(W[k*stride + n]) or 0
__global__ void k_packT(const float* __restrict__ W, unsigned short* __restrict__ WT,
                        int Ksrc, int Nsrc, int stride, int Kpad) {
  int idx = blockIdx.x * 256 + threadIdx.x;
  int n = idx / Kpad, k = idx - n * Kpad;
  float v = (k < Ksrc && n < Nsrc) ? W[(size_t)k * stride + n] : 0.0f;
  WT[idx] = (unsigned short)bf16rne(v);
}

// pack xr/xc (f32) -> bf16 pair, IN PLACE over xr (no restrict: intentional alias)
__global__ void k_packxrc(const float* xr, const float* xc, unsigned* XRC) {
  size_t i = (size_t)blockIdx.x * 512 + threadIdx.x;
  float r = xr[i], c = xc[i];
  XRC[i] = bf16rne(r) | (bf16rne(c) << 16);
}

// ---------------- embedding gather -> bf16, K-padded ----------------
__global__ void k_gather(const int* __restrict__ tokens, const float* __restrict__ emb,
                         unsigned short* __restrict__ xh) {
  int bt = blockIdx.x;
  int tok = tokens[bt];
  const float* src = emb + (size_t)tok * E;
  unsigned short* dst = xh + (size_t)bt * Ep;
  for (int e = threadIdx.x; e < Ep; e += 256)
    dst[e] = (e < E) ? (unsigned short)bf16rne(src[e]) : (unsigned short)0;
}

// ---------------- bf16 MFMA GEMM (round-6 verified) ----------------
__global__ __launch_bounds__(256) void k_gemm_mfma(
    const unsigned short* __restrict__ A1, const unsigned short* __restrict__ B1, int K1, int lda1,
    const unsigned short* __restrict__ A2, const unsigned short* __restrict__ B2, int K2, int lda2,
    const float* __restrict__ bias, const float* __restrict__ Cin,
    float* __restrict__ C, int Nreal, int Cstride)
{
  __shared__ unsigned short As[128][40];
  __shared__ unsigned short Bs[64][40];
  int tid = threadIdx.x;
  int l = tid & 63, w = tid >> 6;
  int row0 = blockIdx.y * 128, col0 = blockIdx.x * 64;
  int lrow = l & 15, lk = (l >> 4) * 8, lq = (l >> 4) * 4;
  int ar = tid >> 1, asg = (tid & 1) * 16;
  int br = tid >> 2, bsg = (tid & 3) * 8;
  f32x4 acc[2][4] = {};
#pragma unroll 1
  for (int pass = 0; pass < 2; ++pass) {
    const unsigned short* A  = pass ? A2 : A1;
    const unsigned short* Bt = pass ? B2 : B1;
    int K   = pass ? K2 : K1;
    int lda = pass ? lda2 : lda1;
    if (K == 0) break;
    for (int k0 = 0; k0 < K; k0 += 32) {
      const uint4* ga = (const uint4*)(A + (size_t)(row0 + ar) * lda + k0 + asg);
      uint4 a0 = ga[0], a1 = ga[1];
      uint4 b0 = *(const uint4*)(Bt + (size_t)(col0 + br) * K + k0 + bsg);
      __syncthreads();
      *(uint4*)&As[ar][asg]     = a0;
      *(uint4*)&As[ar][asg + 8] = a1;
      *(uint4*)&Bs[br][bsg]     = b0;
      __syncthreads();
      short8 av[2], bv[4];
#pragma unroll
      for (int f = 0; f < 2; ++f)
        av[f] = *(const short8*)&As[w * 32 + f * 16 + lrow][lk];
#pragma unroll
      for (int fc = 0; fc < 4; ++fc)
        bv[fc] = *(const short8*)&Bs[fc * 16 + lrow][lk];
#pragma unroll
      for (int f = 0; f < 2; ++f)
#pragma unroll
        for (int fc = 0; fc < 4; ++fc)
          acc[f][fc] = __builtin_amdgcn_mfma_f32_16x16x32_bf16(av[f], bv[fc], acc[f][fc], 0, 0, 0);
    }
  }
#pragma unroll
  for (int f = 0; f < 2; ++f) {
#pragma unroll
    for (int fc = 0; fc < 4; ++fc) {
      int c = col0 + fc * 16 + lrow;
      if (c < Nreal) {
        float bb = bias ? bias[c] : 0.0f;
#pragma unroll
        for (int i = 0; i < 4; ++i) {
          int r = row0 + w * 32 + f * 16 + lq + i;
          if (r < BT) {
            float v = acc[f][fc][i] + bb;
            if (Cin) v += Cin[(size_t)r * Cstride + c];
            C[(size_t)r * Cstride + c] = v;
          }
        }
      }
    }
  }
}

// ---------------- BiLSTM scan (round-6 verified) ----------------
__global__ __launch_bounds__(512) void k_lstm(
    const float* __restrict__ xp_f, const float* __restrict__ xp_b,
    const uint4* __restrict__ PAQ_f, const uint4* __restrict__ PBQ_f,
    const uint4* __restrict__ PAQ_b, const uint4* __restrict__ PBQ_b,
    const int* __restrict__ lengths, unsigned short* __restrict__ factsh)
{
  int b = blockIdx.x;
  int dir = blockIdx.y;
  const float* xp = dir ? xp_b : xp_f;
  const uint4* PAQ = dir ? PAQ_b : PAQ_f;
  const uint4* PBQ = dir ? PBQ_b : PBQ_f;
  int tid = threadIdx.x;
  int j = tid & 255, half = tid >> 8;
  __shared__ float hs[H];
  __shared__ float4 red[512];
  hs[j] = 0.0f;
  float c = 0.0f, h = 0.0f;
  int nsteps = dir ? T : lengths[b];
  const uint4* pa = PAQ + (size_t)(half * 32) * 256 + j;
  const uint4* pb = PBQ + (size_t)(half * 32) * 256 + j;
  const float4* hs4 = reinterpret_cast<const float4*>(hs) + half * 32;
  __syncthreads();
  for (int s = 0; s < nsteps; ++s) {
    int t = dir ? (T - 1 - s) : s;
    float g0 = 0.f, g1 = 0.f, g2 = 0.f, g3 = 0.f;
#pragma unroll 4
    for (int k4 = 0; k4 < 32; ++k4) {
      uint4 a  = pa[(size_t)k4 * 256];
      uint4 bq = pb[(size_t)k4 * 256];
      float4 hv = hs4[k4];
      g0 = fmaf(hv.x, bf_lo(a.x), g0);  g1 = fmaf(hv.x, bf_hi(a.x), g1);
      g2 = fmaf(hv.x, bf_lo(bq.x), g2); g3 = fmaf(hv.x, bf_hi(bq.x), g3);
      g0 = fmaf(hv.y, bf_lo(a.y), g0);  g1 = fmaf(hv.y, bf_hi(a.y), g1);
      g2 = fmaf(hv.y, bf_lo(bq.y), g2); g3 = fmaf(hv.y, bf_hi(bq.y), g3);
      g0 = fmaf(hv.z, bf_lo(a.z), g0);  g1 = fmaf(hv.z, bf_hi(a.z), g1);
      g2 = fmaf(hv.z, bf_lo(bq.z), g2); g3 = fmaf(hv.z, bf_hi(bq.z), g3);
      g0 = fmaf(hv.w, bf_lo(a.w), g0);  g1 = fmaf(hv.w, bf_hi(a.w), g1);
      g2 = fmaf(hv.w, bf_lo(bq.w), g2); g3 = fmaf(hv.w, bf_hi(bq.w), g3);
    }
    red[tid] = make_float4(g0, g1, g2, g3);
    __syncthreads();
    if (half == 0) {
      float4 o = red[tid + 256];
      const float* xrow = xp + (size_t)(b * T + t) * G4;
      g0 += o.x + xrow[j];
      g1 += o.y + xrow[j + 256];
      g2 += o.z + xrow[j + 512];
      g3 += o.w + xrow[j + 768];
      float ig = sigmoidf(g0);
      float fg = sigmoidf(g1);
      float gg = tanhf_fast(g2);
      float og = sigmoidf(g3);
      c = fg * c + ig * gg;
      h = og * tanhf_fast(c);
      hs[j] = h;
      factsh[(size_t)(b * T + t) * D + dir * H + j] = (unsigned short)bf16rne(h);
    }
    __syncthreads();
  }
}

// ---------------- z halves -> bf16 ----------------
__global__ void k_buildz(const unsigned short* __restrict__ factsh, const float* __restrict__ v,
                         unsigned short* __restrict__ za, unsigned short* __restrict__ zb) {
  int bt = blockIdx.x;
  int b = bt / T;
  int d = threadIdx.x;  // 512
  float f = bfu(factsh[(size_t)bt * D + d]);
  float vv = v[(size_t)b * D + d];
  za[(size_t)bt * D + d] = (unsigned short)bf16rne(f * vv);
  zb[(size_t)bt * D + d] = (unsigned short)bf16rne(fabsf(f - vv));
}

// ---------------- score ----------------
__global__ void k_score(const float* __restrict__ att_h, const float* __restrict__ W2,
                        const float* __restrict__ b2, float* __restrict__ s) {
  int bt = blockIdx.x;
  int tid = threadIdx.x;  // 64
  float acc = 0.f;
  for (int e = tid; e < E; e += 64)
    acc += tanhf_fast(att_h[(size_t)bt * E + e]) * W2[e];
  for (int off = 32; off > 0; off >>= 1) acc += __shfl_down(acc, off);
  if (tid == 0) s[bt] = acc + b2[0];
}

// ---------------- masked softmax ----------------
__global__ void k_softmax(const float* __restrict__ s, const int* __restrict__ lengths,
                          float* __restrict__ a) {
  int b = blockIdx.x;
  int t = threadIdx.x;  // 128
  int len = lengths[b];
  __shared__ float wred[2];
  float val = -1e30f;
  if (t < T) val = (t < len) ? s[b * T + t] : -1e9f;
  float mx = val;
  for (int off = 32; off > 0; off >>= 1) mx = fmaxf(mx, __shfl_xor(mx, off));
  int wid = t >> 6, lane = t & 63;
  if (lane == 0) wred[wid] = mx;
  __syncthreads();
  mx = fmaxf(wred[0], wred[1]);
  __syncthreads();
  float e = (t < T && t < len) ? __expf(val - mx) : 0.0f;
  float sum = e;
  for (int off = 32; off > 0; off >>= 1) sum += __shfl_xor(sum, off);
  if (lane == 0) wred[wid] = sum;
  __syncthreads();
  float tot = wred[0] + wred[1];
  if (t < T) a[b * T + t] = e / tot;
}

// ---------------- zero helpers ----------------
__global__ void k_zero(int* __restrict__ p, int n) {
  int i = blockIdx.x * blockDim.x + threadIdx.x;
  if (i < n) p[i] = 0;
}
__global__ void k_ginit(unsigned short* __restrict__ Hb0) {
  Hb0[blockIdx.x * 512 + threadIdx.x] = 0;
}

// ---------------- persistent GRU hop: 32 blocks x 256 thr, 32KB LDS weights --------
// Identical to round 11 EXCEPT Hb is accessed ONLY through agent-scope relaxed
// atomics (sc-bypass: reads/writes hit the device coherence point directly) and
// ALL __threadfence calls are removed. Ordering: __syncthreads drains vmcnt for
// every thread before tid0 publishes the flag; atomic Hin loads cannot be
// speculated above the flag poll. No L2 writeback-invalidate per step.
__global__ __launch_bounds__(256) void k_gru_hop(
    const unsigned short* __restrict__ URCT,   // [1024][512] bf16: UrT | UcT
    unsigned short* __restrict__ Hb,           // [2][B][D] bf16, Hb[0] pre-zeroed
    float* __restrict__ ep,
    const unsigned* __restrict__ XRC,          // [BT][D] bf16 pair (xr,xc)
    const float* __restrict__ br, const float* __restrict__ bc,
    const float* __restrict__ att, int* __restrict__ syncA)  // syncA: 32 flag slots
{
  __shared__ unsigned short Wl[32 * 512];      // 32 KB
  const int tid = threadIdx.x;
  const int bi  = blockIdx.x;                  // 0..31
  const int j0  = bi * 16;
  const int w   = tid >> 6;                    // batch group 0..3
  const int l   = tid & 63;
  const int lrow = l & 15, g = l >> 4;
  const int lq  = g * 4;
  const int j   = j0 + lrow;

  // weights -> LDS (16B-unit XOR swizzle)
  for (int it = tid; it < 32 * 64; it += 256) {
    int row = it >> 6, unit = it & 63;
    int grow = (row < 16) ? (j0 + row) : (512 + j0 + row - 16);
    uint4 v = *(const uint4*)(URCT + (size_t)grow * 512 + unit * 8);
    *(uint4*)&Wl[row * 512 + ((unit ^ (row & 7)) * 8)] = v;
  }

  const float brj = br[j], bcj = bc[j];

  // prefetch gate operands for t = 0 (read-only: normal cached loads)
  unsigned xq[4];
  float gv[4];
#pragma unroll
  for (int i = 0; i < 4; ++i) {
    int b = w * 16 + lq + i;
    gv[i] = att[b * T];
    xq[i] = XRC[(size_t)(b * T) * D + j];
  }
  __syncthreads();   // weights staged (drains prefetch too — overlapped)

  float h[4] = {};
  for (int t = 0; t < T; ++t) {
    const unsigned short* Hin = Hb + (size_t)(t & 1) * (B * D);
    unsigned short*      Hout = Hb + (size_t)((t + 1) & 1) * (B * D);
    // post-barrier critical path: Hin via coherence-point atomic loads
    uint4 a[16];
    const unsigned* hrow = (const unsigned*)(Hin + (size_t)(w * 16 + lrow) * D);
#pragma unroll
    for (int c = 0; c < 16; ++c) {
      const unsigned* src = hrow + c * 16 + g * 4;   // dword units
      a[c].x = __hip_atomic_load(src + 0, __ATOMIC_RELAXED, __HIP_MEMORY_SCOPE_AGENT);
      a[c].y = __hip_atomic_load(src + 1, __ATOMIC_RELAXED, __HIP_MEMORY_SCOPE_AGENT);
      a[c].z = __hip_atomic_load(src + 2, __ATOMIC_RELAXED, __HIP_MEMORY_SCOPE_AGENT);
      a[c].w = __hip_atomic_load(src + 3, __ATOMIC_RELAXED, __HIP_MEMORY_SCOPE_AGENT);
    }
    // issue next step's read-only operand loads (hidden under MFMA + drain)
    unsigned xqn[4] = {};
    float gvn[4] = {};
    if (t + 1 < T) {
#pragma unroll
      for (int i = 0; i < 4; ++i) {
        int b = w * 16 + lq + i;
        gvn[i] = att[b * T + t + 1];
        xqn[i] = XRC[(size_t)(b * T + t + 1) * D + j];
      }
    }
    f32x4 acc[2] = {};
#pragma unroll
    for (int c = 0; c < 16; ++c) {
      short8 av = *(const short8*)&a[c];
#pragma unroll
      for (int fc = 0; fc < 2; ++fc) {
        int row = fc * 16 + lrow;
        short8 bv = *(const short8*)&Wl[row * 512 + (((c * 4 + g) ^ (row & 7)) * 8)];
        acc[fc] = __builtin_amdgcn_mfma_f32_16x16x32_bf16(av, bv, acc[fc], 0, 0, 0);
      }
    }
    // fused gate epilogue: racc = acc[0], cacc = acc[1] (same lane/reg)
#pragma unroll
    for (int i = 0; i < 4; ++i) {
      int b = w * 16 + lq + i;
      float r  = sigmoidf(bf_lo(xq[i]) + acc[0][i] + brj);
      float hc = tanhf_fast(bf_hi(xq[i]) + r * acc[1][i] + bcj);
      float hn = gv[i] * hc + (1.f - gv[i]) * h[i];
      h[i] = hn;
      __hip_atomic_store(&Hout[(size_t)b * D + j], (unsigned short)bf16rne(hn),
                         __ATOMIC_RELAXED, __HIP_MEMORY_SCOPE_AGENT);
    }
    // barrier: __syncthreads drains all threads' write-through stores, then flag
    __syncthreads();
    if (tid == 0)
      __hip_atomic_store(&syncA[bi], t + 1, __ATOMIC_RELAXED, __HIP_MEMORY_SCOPE_AGENT);
    if (tid < 64) {
      bool active = tid < 32;
      while (true) {
        int v = active ? __hip_atomic_load(&syncA[tid], __ATOMIC_RELAXED,
                                           __HIP_MEMORY_SCOPE_AGENT)
                       : 0x7fffffff;
        if (__ballot(active && v <= t) == 0ull) break;   // all flags >= t+1
        __builtin_amdgcn_s_sleep(1);
      }
    }
    __syncthreads();
    // rotate prefetched operands
#pragma unroll
    for (int i = 0; i < 4; ++i) { gv[i] = gvn[i]; xq[i] = xqn[i]; }
  }
#pragma unroll
  for (int i = 0; i < 4; ++i) {
    int b = w * 16 + lq + i;
    ep[(size_t)b * D + j] = h[i];
  }
}

// ---------------- hop projection ----------------
__global__ __launch_bounds__(512) void k_hop(
    const float* __restrict__ m_in, const float* __restrict__ ep,
    const float* __restrict__ q, const float* __restrict__ Whop,
    const float* __restrict__ bhop, float* __restrict__ m_out)
{
  int b = blockIdx.x, j = threadIdx.x;
  __shared__ float av[3 * D];
  av[j]         = m_in[(size_t)b * D + j];
  av[D + j]     = ep[(size_t)b * D + j];
  av[2 * D + j] = q[(size_t)b * D + j];
  __syncthreads();
  float acc = bhop[j];
#pragma unroll 4
  for (int k = 0; k < 3 * D; ++k)
    acc = fmaf(av[k], Whop[(size_t)k * D + j], acc);
  m_out[(size_t)b * D + j] = fmaxf(acc, 0.0f);
}

// ---------------- output ----------------
__global__ void k_out(const float* __restrict__ m, const float* __restrict__ q,
                      const float* __restrict__ Wo, const float* __restrict__ bo,
                      float* __restrict__ out)
{
  int b = blockIdx.x, tid = threadIdx.x;  // 256
  float acc = 0.f;
  for (int k = tid; k < D; k += 256)
    acc += m[(size_t)b * D + k] * Wo[k] + q[(size_t)b * D + k] * Wo[D + k];
  for (int off = 32; off > 0; off >>= 1) acc += __shfl_down(acc, off);
  __shared__ float red[4];
  int wid = tid >> 6, lane = tid & 63;
  if (lane == 0) red[wid] = acc;
  __syncthreads();
  if (tid == 0) {
    float tot = red[0] + red[1] + red[2] + red[3];
    out[b] = 1.0f / (1.0f + __expf(-(tot + bo[0])));
  }
}

extern "C" void kernel_launch(void* const* d_in, const int* in_sizes, int n_in,
                              void* d_out, int out_size, void* d_ws, size_t ws_size,
                              hipStream_t stream)
{
  const int*   tokens  = (const int*)d_in[0];
  const int*   lengths = (const int*)d_in[1];
  const float* emb     = (const float*)d_in[2];
  const float* Wx_f    = (const float*)d_in[3];
  const float* Wh_f    = (const float*)d_in[4];
  const float* b_f     = (const float*)d_in[5];
  const float* Wx_b    = (const float*)d_in[6];
  const float* Wh_b    = (const float*)d_in[7];
  const float* b_b     = (const float*)d_in[8];
  const float* W1      = (const float*)d_in[9];
  const float* b1      = (const float*)d_in[10];
  const float* W2      = (const float*)d_in[11];
  const float* b2      = (const float*)d_in[12];
  const float* Wr      = (const float*)d_in[13];
  const float* Ur      = (const float*)d_in[14];
  const float* br      = (const float*)d_in[15];
  const float* Wc      = (const float*)d_in[16];
  const float* Uc      = (const float*)d_in[17];
  const float* bc      = (const float*)d_in[18];
  const float* q       = (const float*)d_in[19];
  const float* W_hops  = (const float*)d_in[20];
  const float* b_hops  = (const float*)d_in[21];
  const float* Wo      = (const float*)d_in[22];
  const float* bo      = (const float*)d_in[23];
  float* ws = (float*)d_ws;

  // ---- workspace layout ----
  float* p = ws;
  unsigned short* xh = (unsigned short*)p;  p += (size_t)Mp * Ep / 2;
  float* xp_f   = p;  p += (size_t)BT * G4;                                 // later: xr | xc -> XRC
  float* xp_b   = p;  p += (size_t)BT * G4;                                 // later: za | zb
  unsigned short* factsh = (unsigned short*)p;  p += (size_t)Mp * D / 2;
  float* att_h  = p;  p += (size_t)BT * E;
  float* part0  = p;  p += (size_t)BT * E;
  float* scores = p;  p += BT;
  float* att    = p;  p += BT;
  float* m0     = p;  p += (size_t)B * D;
  float* m1     = p;  p += (size_t)B * D;
  float* epb    = p;  p += (size_t)B * D;
  unsigned short* Hb = (unsigned short*)p;  p += (size_t)2 * B * D / 2;     // [2][B][D] bf16
  int* syncA    = (int*)p;  p += 3 * 128;
  uint4* PAQ_f  = (uint4*)p;  p += (size_t)(H / 4) * 256 * 4;
  uint4* PBQ_f  = (uint4*)p;  p += (size_t)(H / 4) * 256 * 4;
  uint4* PAQ_b  = (uint4*)p;  p += (size_t)(H / 4) * 256 * 4;
  uint4* PBQ_b  = (uint4*)p;  p += (size_t)(H / 4) * 256 * 4;
  unsigned short* WxT_f = (unsigned short*)p;  p += (size_t)G4 * Ep / 2;
  unsigned short* WxT_b = (unsigned short*)p;  p += (size_t)G4 * Ep / 2;
  unsigned short* WrT   = (unsigned short*)p;  p += (size_t)D * D / 2;
  unsigned short* WcT   = (unsigned short*)p;  p += (size_t)D * D / 2;
  unsigned short* URCT  = (unsigned short*)p;  p += (size_t)(2 * D) * D / 2; // [1024][512]
  unsigned short* W1T[4];
  for (int c = 0; c < 4; ++c) { W1T[c] = (unsigned short*)p; p += (size_t)Ep * D / 2; }
  float* xr = xp_f;
  float* xc = xp_f + (size_t)BT * D;
  unsigned* XRC = (unsigned*)xr;               // in-place bf16-pair pack over xr
  unsigned short* za = (unsigned short*)xp_b;
  unsigned short* zb = (unsigned short*)xp_b + (size_t)Mp * D;

  // 0) zero barrier flags + pack weights
  k_zero<<<1, 384, 0, stream>>>(syncA, 3 * 128);
  k_pack_lstm<<<(H / 4) * 256 / 256, 256, 0, stream>>>(Wh_f, PAQ_f, PBQ_f);
  k_pack_lstm<<<(H / 4) * 256 / 256, 256, 0, stream>>>(Wh_b, PAQ_b, PBQ_b);
  k_packT<<<G4 * Ep / 256, 256, 0, stream>>>(Wx_f, WxT_f, E, G4, G4, Ep);
  k_packT<<<G4 * Ep / 256, 256, 0, stream>>>(Wx_b, WxT_b, E, G4, G4, Ep);
  k_packT<<<D * D / 256, 256, 0, stream>>>(Wr, WrT, D, D, D, D);
  k_packT<<<D * D / 256, 256, 0, stream>>>(Wc, WcT, D, D, D, D);
  k_packT<<<D * D / 256, 256, 0, stream>>>(Ur, URCT, D, D, D, D);
  k_packT<<<D * D / 256, 256, 0, stream>>>(Uc, URCT + (size_t)D * D, D, D, D, D);
  for (int c = 0; c < 4; ++c)
    k_packT<<<Ep * D / 256, 256, 0, stream>>>(W1 + (size_t)c * D * E, W1T[c], D, E, E, D);

  // 1) embed + input projections (MFMA)
  k_gather<<<BT, 256, 0, stream>>>(tokens, emb, xh);
  k_gemm_mfma<<<dim3(G4 / 64, Mp / 128), 256, 0, stream>>>(
      xh, WxT_f, Ep, Ep, nullptr, nullptr, 0, 0, b_f, nullptr, xp_f, G4, G4);
  k_gemm_mfma<<<dim3(G4 / 64, Mp / 128), 256, 0, stream>>>(
      xh, WxT_b, Ep, Ep, nullptr, nullptr, 0, 0, b_b, nullptr, xp_b, G4, G4);
  // 2) BiLSTM
  k_lstm<<<dim3(B, 2), 512, 0, stream>>>(xp_f, xp_b, PAQ_f, PBQ_f, PAQ_b, PBQ_b, lengths, factsh);
  // 3) hop-invariant precomputes (MFMA); then pack xr/xc -> bf16 pairs in place
  k_gemm_mfma<<<dim3(D / 64, Mp / 128), 256, 0, stream>>>(
      factsh, WrT, D, D, nullptr, nullptr, 0, 0, nullptr, nullptr, xr, D, D);
  k_gemm_mfma<<<dim3(D / 64, Mp / 128), 256, 0, stream>>>(
      factsh, WcT, D, D, nullptr, nullptr, 0, 0, nullptr, nullptr, xc, D, D);
  k_packxrc<<<BT * D / 512, 512, 0, stream>>>(xr, xc, XRC);
  k_buildz<<<BT, 512, 0, stream>>>(factsh, q, za, zb);
  k_gemm_mfma<<<dim3(Ep / 64, Mp / 128), 256, 0, stream>>>(
      za, W1T[0], D, D, zb, W1T[2], D, D, b1, nullptr, part0, E, E);

  // 4) hops
  const float* m_in = q;
  float* mb[2] = {m0, m1};
  for (int i = 0; i < NH; ++i) {
    k_buildz<<<BT, 512, 0, stream>>>(factsh, m_in, za, zb);
    k_gemm_mfma<<<dim3(Ep / 64, Mp / 128), 256, 0, stream>>>(
        za, W1T[1], D, D, zb, W1T[3], D, D, nullptr, part0, att_h, E, E);
    k_score<<<BT, 64, 0, stream>>>(att_h, W2, b2, scores);
    k_softmax<<<B, 128, 0, stream>>>(scores, lengths, att);
    // GRU: single persistent kernel per hop (32 blocks, fence-free atomics)
    k_ginit<<<B * D / 512, 512, 0, stream>>>(Hb);
    k_gru_hop<<<32, 256, 0, stream>>>(URCT, Hb, epb, XRC, br, bc, att, syncA + i * 128);
    k_hop<<<B, 512, 0, stream>>>(m_in, epb, q,
                                 W_hops + (size_t)i * 3 * D * D, b_hops + (size_t)i * D,
                                 mb[i & 1]);
    m_in = mb[i & 1];
  }
  // 5) output
  k_out<<<B, 256, 0, stream>>>(m_in, q, Wo, bo, (float*)d_out);
}

// Round 13
// 3978.539 us; speedup vs baseline: 1.1553x; 1.1553x over previous
//
#include <hip/hip_runtime.h>

constexpr int B  = 64;
constexpr int T  = 121;
constexpr int E  = 300;
constexpr int Ep = 320;    // E padded to K-chunk multiple
constexpr int H  = 256;
constexpr int G4 = 1024;   // 4*H
constexpr int D  = 512;    // 2*H
constexpr int NH = 3;
constexpr int BT = B * T;  // 7744
constexpr int Mp = 7808;   // 61*128, M padded for 128-row tiles

using short8 = __attribute__((ext_vector_type(8))) short;
using f32x4  = __attribute__((ext_vector_type(4))) float;

__device__ __forceinline__ float sigmoidf(float x) { return 1.0f / (1.0f + __expf(-x)); }
__device__ __forceinline__ float tanhf_fast(float x) {
  float e = __expf(2.0f * x);
  return 1.0f - 2.0f / (e + 1.0f);
}
__device__ __forceinline__ unsigned bf16rne(float x) {
  unsigned u = __float_as_uint(x);
  return (u + 0x7fffu + ((u >> 16) & 1u)) >> 16;
}
__device__ __forceinline__ float bf_lo(unsigned u) { return __uint_as_float(u << 16); }
__device__ __forceinline__ float bf_hi(unsigned u) { return __uint_as_float(u & 0xffff0000u); }
__device__ __forceinline__ float bfu(unsigned short u) { return __uint_as_float(((unsigned)u) << 16); }

#if defined(__has_builtin)
#if __has_builtin(__builtin_amdgcn_cvt_f32_ubyte0)
#define HAS_UBYTE 1
#endif
#endif
#ifdef HAS_UBYTE
__device__ __forceinline__ float UB0(unsigned u) { return __builtin_amdgcn_cvt_f32_ubyte0(u); }
__device__ __forceinline__ float UB1(unsigned u) { return __builtin_amdgcn_cvt_f32_ubyte1(u); }
__device__ __forceinline__ float UB2(unsigned u) { return __builtin_amdgcn_cvt_f32_ubyte2(u); }
__device__ __forceinline__ float UB3(unsigned u) { return __builtin_amdgcn_cvt_f32_ubyte3(u); }
#else
__device__ __forceinline__ float UB0(unsigned u) { return (float)(u & 0xffu); }
__device__ __forceinline__ float UB1(unsigned u) { return (float)((u >> 8) & 0xffu); }
__device__ __forceinline__ float UB2(unsigned u) { return (float)((u >> 16) & 0xffu); }
__device__ __forceinline__ float UB3(unsigned u) { return (float)((u >> 24) & 0xffu); }
#endif

// ---------------- weight packing ----------------
// LSTM: bf16 pair-packed, uint4-grouped (round-4 verified)
__global__ void k_pack_lstm(const float* __restrict__ Wh,
                            uint4* __restrict__ PAQ, uint4* __restrict__ PBQ) {
  int idx = blockIdx.x * 256 + threadIdx.x;   // over (H/4)*256 = 16384
  int k4 = idx >> 8, j = idx & 255;
  int k = 4 * k4;
  uint4 a, bq;
  const float* r0 = Wh + (size_t)(k + 0) * G4;
  const float* r1 = Wh + (size_t)(k + 1) * G4;
  const float* r2 = Wh + (size_t)(k + 2) * G4;
  const float* r3 = Wh + (size_t)(k + 3) * G4;
  a.x  = bf16rne(r0[j]) | (bf16rne(r0[j + 256]) << 16);
  a.y  = bf16rne(r1[j]) | (bf16rne(r1[j + 256]) << 16);
  a.z  = bf16rne(r2[j]) | (bf16rne(r2[j + 256]) << 16);
  a.w  = bf16rne(r3[j]) | (bf16rne(r3[j + 256]) << 16);
  bq.x = bf16rne(r0[j + 512]) | (bf16rne(r0[j + 768]) << 16);
  bq.y = bf16rne(r1[j + 512]) | (bf16rne(r1[j + 768]) << 16);
  bq.z = bf16rne(r2[j + 512]) | (bf16rne(r2[j + 768]) << 16);
  bq.w = bf16rne(r3[j + 512]) | (bf16rne(r3[j + 768]) << 16);
  PAQ[idx] = a;
  PBQ[idx] = bq;
}

// generic B^T bf16 pack with zero padding: WT[n*Kpad + k] = bf16(W[k*stride + n]) or 0
__global__ void k_packT(const float* __restrict__ W, unsigned short* __restrict__ WT,
                        int Ksrc, int Nsrc, int stride, int Kpad) {
  int idx = blockIdx.x * 256 + threadIdx.x;
  int n = idx / Kpad, k = idx - n * Kpad;
  float v = (k < Ksrc && n < Nsrc) ? W[(size_t)k * stride + n] : 0.0f;
  WT[idx] = (unsigned short)bf16rne(v);
}

// pack xr/xc (f32) -> bf16 pair, IN PLACE over xr (no restrict: intentional alias)
__global__ void k_packxrc(const float* xr, const float* xc, unsigned* XRC) {
  size_t i = (size_t)blockIdx.x * 512 + threadIdx.x;
  float r = xr[i], c = xc[i];
  XRC[i] = bf16rne(r) | (bf16rne(c) << 16);
}

// absmax of Ur/Uc (uint-bit compare valid for non-negative floats)
__global__ void k_scales(const float* __restrict__ Ur, const float* __restrict__ Uc,
                         unsigned* __restrict__ smax) {
  int i = blockIdx.x * 256 + threadIdx.x;     // over D*D
  unsigned a = __float_as_uint(fabsf(Ur[i]));
  unsigned b = __float_as_uint(fabsf(Uc[i]));
  for (int off = 32; off > 0; off >>= 1) {
    a = max(a, (unsigned)__shfl_xor((int)a, off));
    b = max(b, (unsigned)__shfl_xor((int)b, off));
  }
  if ((threadIdx.x & 63) == 0) {
    atomicMax(&smax[0], a);
    atomicMax(&smax[1], b);
  }
}

// GRU int8 pack: UQ8[k8*D + j] = uint4, dword d holds k=8*k8+2d,2d+1 as
// bytes (r(k),c(k),r(k+1),c(k+1)), q = round(w*127/max)+128 in [1,255].
__global__ void k_pack_gru8(const float* __restrict__ Ur, const float* __restrict__ Uc,
                            const unsigned* __restrict__ smax, uint4* __restrict__ UQ8) {
  int idx = blockIdx.x * 256 + threadIdx.x;   // over (D/8)*D = 32768
  int k8 = idx >> 9, j = idx & 511;
  float invr = 127.0f / __uint_as_float(smax[0]);
  float invc = 127.0f / __uint_as_float(smax[1]);
  unsigned dw[4];
#pragma unroll
  for (int d = 0; d < 4; ++d) {
    int k0 = k8 * 8 + 2 * d;
    unsigned r0 = (unsigned)(__float2int_rn(Ur[(size_t)k0 * D + j] * invr) + 128);
    unsigned c0 = (unsigned)(__float2int_rn(Uc[(size_t)k0 * D + j] * invc) + 128);
    unsigned r1 = (unsigned)(__float2int_rn(Ur[(size_t)(k0 + 1) * D + j] * invr) + 128);
    unsigned c1 = (unsigned)(__float2int_rn(Uc[(size_t)(k0 + 1) * D + j] * invc) + 128);
    dw[d] = r0 | (c0 << 8) | (r1 << 16) | (c1 << 24);
  }
  UQ8[idx] = make_uint4(dw[0], dw[1], dw[2], dw[3]);
}

// ---------------- embedding gather -> bf16, K-padded ----------------
__global__ void k_gather(const int* __restrict__ tokens, const float* __restrict__ emb,
                         unsigned short* __restrict__ xh) {
  int bt = blockIdx.x;
  int tok = tokens[bt];
  const float* src = emb + (size_t)tok * E;
  unsigned short* dst = xh + (size_t)bt * Ep;
  for (int e = threadIdx.x; e < Ep; e += 256)
    dst[e] = (e < E) ? (unsigned short)bf16rne(src[e]) : (unsigned short)0;
}

// ---------------- bf16 MFMA GEMM (round-6 verified) ----------------
__global__ __launch_bounds__(256) void k_gemm_mfma(
    const unsigned short* __restrict__ A1, const unsigned short* __restrict__ B1, int K1, int lda1,
    const unsigned short* __restrict__ A2, const unsigned short* __restrict__ B2, int K2, int lda2,
    const float* __restrict__ bias, const float* __restrict__ Cin,
    float* __restrict__ C, int Nreal, int Cstride)
{
  __shared__ unsigned short As[128][40];
  __shared__ unsigned short Bs[64][40];
  int tid = threadIdx.x;
  int l = tid & 63, w = tid >> 6;
  int row0 = blockIdx.y * 128, col0 = blockIdx.x * 64;
  int lrow = l & 15, lk = (l >> 4) * 8, lq = (l >> 4) * 4;
  int ar = tid >> 1, asg = (tid & 1) * 16;
  int br = tid >> 2, bsg = (tid & 3) * 8;
  f32x4 acc[2][4] = {};
#pragma unroll 1
  for (int pass = 0; pass < 2; ++pass) {
    const unsigned short* A  = pass ? A2 : A1;
    const unsigned short* Bt = pass ? B2 : B1;
    int K   = pass ? K2 : K1;
    int lda = pass ? lda2 : lda1;
    if (K == 0) break;
    for (int k0 = 0; k0 < K; k0 += 32) {
      const uint4* ga = (const uint4*)(A + (size_t)(row0 + ar) * lda + k0 + asg);
      uint4 a0 = ga[0], a1 = ga[1];
      uint4 b0 = *(const uint4*)(Bt + (size_t)(col0 + br) * K + k0 + bsg);
      __syncthreads();
      *(uint4*)&As[ar][asg]     = a0;
      *(uint4*)&As[ar][asg + 8] = a1;
      *(uint4*)&Bs[br][bsg]     = b0;
      __syncthreads();
      short8 av[2], bv[4];
#pragma unroll
      for (int f = 0; f < 2; ++f)
        av[f] = *(const short8*)&As[w * 32 + f * 16 + lrow][lk];
#pragma unroll
      for (int fc = 0; fc < 4; ++fc)
        bv[fc] = *(const short8*)&Bs[fc * 16 + lrow][lk];
#pragma unroll
      for (int f = 0; f < 2; ++f)
#pragma unroll
        for (int fc = 0; fc < 4; ++fc)
          acc[f][fc] = __builtin_amdgcn_mfma_f32_16x16x32_bf16(av[f], bv[fc], acc[f][fc], 0, 0, 0);
    }
  }
#pragma unroll
  for (int f = 0; f < 2; ++f) {
#pragma unroll
    for (int fc = 0; fc < 4; ++fc) {
      int c = col0 + fc * 16 + lrow;
      if (c < Nreal) {
        float bb = bias ? bias[c] : 0.0f;
#pragma unroll
        for (int i = 0; i < 4; ++i) {
          int r = row0 + w * 32 + f * 16 + lq + i;
          if (r < BT) {
            float v = acc[f][fc][i] + bb;
            if (Cin) v += Cin[(size_t)r * Cstride + c];
            C[(size_t)r * Cstride + c] = v;
          }
        }
      }
    }
  }
}

// ---------------- BiLSTM scan (round-6 verified) ----------------
__global__ __launch_bounds__(512) void k_lstm(
    const float* __restrict__ xp_f, const float* __restrict__ xp_b,
    const uint4* __restrict__ PAQ_f, const uint4* __restrict__ PBQ_f,
    const uint4* __restrict__ PAQ_b, const uint4* __restrict__ PBQ_b,
    const int* __restrict__ lengths, unsigned short* __restrict__ factsh)
{
  int b = blockIdx.x;
  int dir = blockIdx.y;
  const float* xp = dir ? xp_b : xp_f;
  const uint4* PAQ = dir ? PAQ_b : PAQ_f;
  const uint4* PBQ = dir ? PBQ_b : PBQ_f;
  int tid = threadIdx.x;
  int j = tid & 255, half = tid >> 8;
  __shared__ float hs[H];
  __shared__ float4 red[512];
  hs[j] = 0.0f;
  float c = 0.0f, h = 0.0f;
  int nsteps = dir ? T : lengths[b];
  const uint4* pa = PAQ + (size_t)(half * 32) * 256 + j;
  const uint4* pb = PBQ + (size_t)(half * 32) * 256 + j;
  const float4* hs4 = reinterpret_cast<const float4*>(hs) + half * 32;
  __syncthreads();
  for (int s = 0; s < nsteps; ++s) {
    int t = dir ? (T - 1 - s) : s;
    float g0 = 0.f, g1 = 0.f, g2 = 0.f, g3 = 0.f;
#pragma unroll 4
    for (int k4 = 0; k4 < 32; ++k4) {
      uint4 a  = pa[(size_t)k4 * 256];
      uint4 bq = pb[(size_t)k4 * 256];
      float4 hv = hs4[k4];
      g0 = fmaf(hv.x, bf_lo(a.x), g0);  g1 = fmaf(hv.x, bf_hi(a.x), g1);
      g2 = fmaf(hv.x, bf_lo(bq.x), g2); g3 = fmaf(hv.x, bf_hi(bq.x), g3);
      g0 = fmaf(hv.y, bf_lo(a.y), g0);  g1 = fmaf(hv.y, bf_hi(a.y), g1);
      g2 = fmaf(hv.y, bf_lo(bq.y), g2); g3 = fmaf(hv.y, bf_hi(bq.y), g3);
      g0 = fmaf(hv.z, bf_lo(a.z), g0);  g1 = fmaf(hv.z, bf_hi(a.z), g1);
      g2 = fmaf(hv.z, bf_lo(bq.z), g2); g3 = fmaf(hv.z, bf_hi(bq.z), g3);
      g0 = fmaf(hv.w, bf_lo(a.w), g0);  g1 = fmaf(hv.w, bf_hi(a.w), g1);
      g2 = fmaf(hv.w, bf_lo(bq.w), g2); g3 = fmaf(hv.w, bf_hi(bq.w), g3);
    }
    red[tid] = make_float4(g0, g1, g2, g3);
    __syncthreads();
    if (half == 0) {
      float4 o = red[tid + 256];
      const float* xrow = xp + (size_t)(b * T + t) * G4;
      g0 += o.x + xrow[j];
      g1 += o.y + xrow[j + 256];
      g2 += o.z + xrow[j + 512];
      g3 += o.w + xrow[j + 768];
      float ig = sigmoidf(g0);
      float fg = sigmoidf(g1);
      float gg = tanhf_fast(g2);
      float og = sigmoidf(g3);
      c = fg * c + ig * gg;
      h = og * tanhf_fast(c);
      hs[j] = h;
      factsh[(size_t)(b * T + t) * D + dir * H + j] = (unsigned short)bf16rne(h);
    }
    __syncthreads();
  }
}

// ---------------- z halves -> bf16 ----------------
__global__ void k_buildz(const unsigned short* __restrict__ factsh, const float* __restrict__ v,
                         unsigned short* __restrict__ za, unsigned short* __restrict__ zb) {
  int bt = blockIdx.x;
  int b = bt / T;
  int d = threadIdx.x;  // 512
  float f = bfu(factsh[(size_t)bt * D + d]);
  float vv = v[(size_t)b * D + d];
  za[(size_t)bt * D + d] = (unsigned short)bf16rne(f * vv);
  zb[(size_t)bt * D + d] = (unsigned short)bf16rne(fabsf(f - vv));
}

// ---------------- score ----------------
__global__ void k_score(const float* __restrict__ att_h, const float* __restrict__ W2,
                        const float* __restrict__ b2, float* __restrict__ s) {
  int bt = blockIdx.x;
  int tid = threadIdx.x;  // 64
  float acc = 0.f;
  for (int e = tid; e < E; e += 64)
    acc += tanhf_fast(att_h[(size_t)bt * E + e]) * W2[e];
  for (int off = 32; off > 0; off >>= 1) acc += __shfl_down(acc, off);
  if (tid == 0) s[bt] = acc + b2[0];
}

// ---------------- masked softmax ----------------
__global__ void k_softmax(const float* __restrict__ s, const int* __restrict__ lengths,
                          float* __restrict__ a) {
  int b = blockIdx.x;
  int t = threadIdx.x;  // 128
  int len = lengths[b];
  __shared__ float wred[2];
  float val = -1e30f;
  if (t < T) val = (t < len) ? s[b * T + t] : -1e9f;
  float mx = val;
  for (int off = 32; off > 0; off >>= 1) mx = fmaxf(mx, __shfl_xor(mx, off));
  int wid = t >> 6, lane = t & 63;
  if (lane == 0) wred[wid] = mx;
  __syncthreads();
  mx = fmaxf(wred[0], wred[1]);
  __syncthreads();
  float e = (t < T && t < len) ? __expf(val - mx) : 0.0f;
  float sum = e;
  for (int off = 32; off > 0; off >>= 1) sum += __shfl_xor(sum, off);
  if (lane == 0) wred[wid] = sum;
  __syncthreads();
  float tot = wred[0] + wred[1];
  if (t < T) a[b * T + t] = e / tot;
}

// ---------------- zero helper ----------------
__global__ void k_zero(int* __restrict__ p, int n) {
  int i = blockIdx.x * blockDim.x + threadIdx.x;
  if (i < n) p[i] = 0;
}

// ---------------- attention GRU: per-batch streaming, int8 weights ----------------
// One block (1024 thr) per batch; no cross-block sync. tid&511 = column j,
// tid>>9 = k-half. 512KB int8 U stream per step from L2; h fp32 in LDS.
// Zero-point correction: racc = s*(q - 128*sum(h)); sum(h) computed by wave 0
// after each h update (hidden behind the other 15 waves). att==0 for t>=len
// freezes h -> early exit at len.
__global__ __launch_bounds__(1024) void k_gru(
    const unsigned* __restrict__ XRC, const uint4* __restrict__ UQ8,
    const unsigned* __restrict__ smax,
    const float* __restrict__ br, const float* __restrict__ bc,
    const float* __restrict__ att, const int* __restrict__ lengths,
    float* __restrict__ ep)
{
  int b = blockIdx.x;
  int tid = threadIdx.x;
  int j = tid & 511, half = tid >> 9;
  __shared__ float hs[D];
  __shared__ float2 red[1024];
  __shared__ float hsL;
  if (half == 0) hs[j] = 0.0f;
  if (tid == 0) hsL = 0.0f;
  float hj = 0.0f;
  int len = lengths[b];
  float s_r = __uint_as_float(smax[0]) * (1.0f / 127.0f);
  float s_c = __uint_as_float(smax[1]) * (1.0f / 127.0f);
  float brj = br[j], bcj = bc[j];
  const uint4* up = UQ8 + (size_t)(half * 32) * 512 + j;
  const float4* hs4 = reinterpret_cast<const float4*>(hs);
  __syncthreads();
  for (int t = 0; t < len; ++t) {
    float g = att[b * T + t];
    unsigned xq = XRC[(size_t)(b * T + t) * D + j];
    float qr = 0.f, qc = 0.f;
#pragma unroll 8
    for (int k8 = 0; k8 < 32; ++k8) {
      uint4 u = up[(size_t)k8 * 512];
      float4 h0 = hs4[(half * 32 + k8) * 2];
      float4 h1 = hs4[(half * 32 + k8) * 2 + 1];
      qr = fmaf(h0.x, UB0(u.x), qr); qc = fmaf(h0.x, UB1(u.x), qc);
      qr = fmaf(h0.y, UB2(u.x), qr); qc = fmaf(h0.y, UB3(u.x), qc);
      qr = fmaf(h0.z, UB0(u.y), qr); qc = fmaf(h0.z, UB1(u.y), qc);
      qr = fmaf(h0.w, UB2(u.y), qr); qc = fmaf(h0.w, UB3(u.y), qc);
      qr = fmaf(h1.x, UB0(u.z), qr); qc = fmaf(h1.x, UB1(u.z), qc);
      qr = fmaf(h1.y, UB2(u.z), qr); qc = fmaf(h1.y, UB3(u.z), qc);
      qr = fmaf(h1.z, UB0(u.w), qr); qc = fmaf(h1.z, UB1(u.w), qc);
      qr = fmaf(h1.w, UB2(u.w), qr); qc = fmaf(h1.w, UB3(u.w), qc);
    }
    red[tid] = make_float2(qr, qc);
    __syncthreads();
    if (half == 0) {
      float2 o = red[tid + 512];
      float hsum = hsL;
      float racc = s_r * (qr + o.x - 128.0f * hsum);
      float cacc = s_c * (qc + o.y - 128.0f * hsum);
      float r  = sigmoidf(bf_lo(xq) + racc + brj);
      float hc = tanhf_fast(bf_hi(xq) + r * cacc + bcj);
      hj = g * hc + (1.f - g) * hj;
      hs[j] = hj;
    }
    __syncthreads();
    // wave 0: sum of new h state for next step's zero-point correction
    if (tid < 64) {
      float4 a = hs4[2 * tid], bq = hs4[2 * tid + 1];
      float s4 = ((a.x + a.y) + (a.z + a.w)) + ((bq.x + bq.y) + (bq.z + bq.w));
      for (int off = 32; off > 0; off >>= 1) s4 += __shfl_down(s4, off);
      if (tid == 0) hsL = s4;
    }
  }
  if (half == 0) ep[(size_t)b * D + j] = hj;
}

// ---------------- hop projection ----------------
__global__ __launch_bounds__(512) void k_hop(
    const float* __restrict__ m_in, const float* __restrict__ ep,
    const float* __restrict__ q, const float* __restrict__ Whop,
    const float* __restrict__ bhop, float* __restrict__ m_out)
{
  int b = blockIdx.x, j = threadIdx.x;
  __shared__ float av[3 * D];
  av[j]         = m_in[(size_t)b * D + j];
  av[D + j]     = ep[(size_t)b * D + j];
  av[2 * D + j] = q[(size_t)b * D + j];
  __syncthreads();
  float acc = bhop[j];
#pragma unroll 4
  for (int k = 0; k < 3 * D; ++k)
    acc = fmaf(av[k], Whop[(size_t)k * D + j], acc);
  m_out[(size_t)b * D + j] = fmaxf(acc, 0.0f);
}

// ---------------- output ----------------
__global__ void k_out(const float* __restrict__ m, const float* __restrict__ q,
                      const float* __restrict__ Wo, const float* __restrict__ bo,
                      float* __restrict__ out)
{
  int b = blockIdx.x, tid = threadIdx.x;  // 256
  float acc = 0.f;
  for (int k = tid; k < D; k += 256)
    acc += m[(size_t)b * D + k] * Wo[k] + q[(size_t)b * D + k] * Wo[D + k];
  for (int off = 32; off > 0; off >>= 1) acc += __shfl_down(acc, off);
  __shared__ float red[4];
  int wid = tid >> 6, lane = tid & 63;
  if (lane == 0) red[wid] = acc;
  __syncthreads();
  if (tid == 0) {
    float tot = red[0] + red[1] + red[2] + red[3];
    out[b] = 1.0f / (1.0f + __expf(-(tot + bo[0])));
  }
}

extern "C" void kernel_launch(void* const* d_in, const int* in_sizes, int n_in,
                              void* d_out, int out_size, void* d_ws, size_t ws_size,
                              hipStream_t stream)
{
  const int*   tokens  = (const int*)d_in[0];
  const int*   lengths = (const int*)d_in[1];
  const float* emb     = (const float*)d_in[2];
  const float* Wx_f    = (const float*)d_in[3];
  const float* Wh_f    = (const float*)d_in[4];
  const float* b_f     = (const float*)d_in[5];
  const float* Wx_b    = (const float*)d_in[6];
  const float* Wh_b    = (const float*)d_in[7];
  const float* b_b     = (const float*)d_in[8];
  const float* W1      = (const float*)d_in[9];
  const float* b1      = (const float*)d_in[10];
  const float* W2      = (const float*)d_in[11];
  const float* b2      = (const float*)d_in[12];
  const float* Wr      = (const float*)d_in[13];
  const float* Ur      = (const float*)d_in[14];
  const float* br      = (const float*)d_in[15];
  const float* Wc      = (const float*)d_in[16];
  const float* Uc      = (const float*)d_in[17];
  const float* bc      = (const float*)d_in[18];
  const float* q       = (const float*)d_in[19];
  const float* W_hops  = (const float*)d_in[20];
  const float* b_hops  = (const float*)d_in[21];
  const float* Wo      = (const float*)d_in[22];
  const float* bo      = (const float*)d_in[23];
  float* ws = (float*)d_ws;

  // ---- workspace layout ----
  float* p = ws;
  unsigned short* xh = (unsigned short*)p;  p += (size_t)Mp * Ep / 2;
  float* xp_f   = p;  p += (size_t)BT * G4;                                 // later: xr | xc -> XRC
  float* xp_b   = p;  p += (size_t)BT * G4;                                 // later: za | zb
  unsigned short* factsh = (unsigned short*)p;  p += (size_t)Mp * D / 2;
  float* att_h  = p;  p += (size_t)BT * E;
  float* part0  = p;  p += (size_t)BT * E;
  float* scores = p;  p += BT;
  float* att    = p;  p += BT;
  float* m0     = p;  p += (size_t)B * D;
  float* m1     = p;  p += (size_t)B * D;
  float* epb    = p;  p += (size_t)B * D;
  unsigned* smax = (unsigned*)p;  p += 4;
  uint4* UQ8    = (uint4*)p;  p += (size_t)(D / 8) * D * 4;                 // 512KB int8 GRU weights
  uint4* PAQ_f  = (uint4*)p;  p += (size_t)(H / 4) * 256 * 4;
  uint4* PBQ_f  = (uint4*)p;  p += (size_t)(H / 4) * 256 * 4;
  uint4* PAQ_b  = (uint4*)p;  p += (size_t)(H / 4) * 256 * 4;
  uint4* PBQ_b  = (uint4*)p;  p += (size_t)(H / 4) * 256 * 4;
  unsigned short* WxT_f = (unsigned short*)p;  p += (size_t)G4 * Ep / 2;
  unsigned short* WxT_b = (unsigned short*)p;  p += (size_t)G4 * Ep / 2;
  unsigned short* WrT   = (unsigned short*)p;  p += (size_t)D * D / 2;
  unsigned short* WcT   = (unsigned short*)p;  p += (size_t)D * D / 2;
  unsigned short* W1T[4];
  for (int c = 0; c < 4; ++c) { W1T[c] = (unsigned short*)p; p += (size_t)Ep * D / 2; }
  float* xr = xp_f;
  float* xc = xp_f + (size_t)BT * D;
  unsigned* XRC = (unsigned*)xr;               // in-place bf16-pair pack over xr
  unsigned short* za = (unsigned short*)xp_b;
  unsigned short* zb = (unsigned short*)xp_b + (size_t)Mp * D;

  // 0) scales + pack weights (GRU int8; LSTM bf16; GEMM weights bf16^T)
  k_zero<<<1, 64, 0, stream>>>((int*)smax, 4);
  k_scales<<<D * D / 256, 256, 0, stream>>>(Ur, Uc, smax);
  k_pack_gru8<<<(D / 8) * D / 256, 256, 0, stream>>>(Ur, Uc, smax, UQ8);
  k_pack_lstm<<<(H / 4) * 256 / 256, 256, 0, stream>>>(Wh_f, PAQ_f, PBQ_f);
  k_pack_lstm<<<(H / 4) * 256 / 256, 256, 0, stream>>>(Wh_b, PAQ_b, PBQ_b);
  k_packT<<<G4 * Ep / 256, 256, 0, stream>>>(Wx_f, WxT_f, E, G4, G4, Ep);
  k_packT<<<G4 * Ep / 256, 256, 0, stream>>>(Wx_b, WxT_b, E, G4, G4, Ep);
  k_packT<<<D * D / 256, 256, 0, stream>>>(Wr, WrT, D, D, D, D);
  k_packT<<<D * D / 256, 256, 0, stream>>>(Wc, WcT, D, D, D, D);
  for (int c = 0; c < 4; ++c)
    k_packT<<<Ep * D / 256, 256, 0, stream>>>(W1 + (size_t)c * D * E, W1T[c], D, E, E, D);

  // 1) embed + input projections (MFMA)
  k_gather<<<BT, 256, 0, stream>>>(tokens, emb, xh);
  k_gemm_mfma<<<dim3(G4 / 64, Mp / 128), 256, 0, stream>>>(
      xh, WxT_f, Ep, Ep, nullptr, nullptr, 0, 0, b_f, nullptr, xp_f, G4, G4);
  k_gemm_mfma<<<dim3(G4 / 64, Mp / 128), 256, 0, stream>>>(
      xh, WxT_b, Ep, Ep, nullptr, nullptr, 0, 0, b_b, nullptr, xp_b, G4, G4);
  // 2) BiLSTM
  k_lstm<<<dim3(B, 2), 512, 0, stream>>>(xp_f, xp_b, PAQ_f, PBQ_f, PAQ_b, PBQ_b, lengths, factsh);
  // 3) hop-invariant precomputes (MFMA); then pack xr/xc -> bf16 pairs in place
  k_gemm_mfma<<<dim3(D / 64, Mp / 128), 256, 0, stream>>>(
      factsh, WrT, D, D, nullptr, nullptr, 0, 0, nullptr, nullptr, xr, D, D);
  k_gemm_mfma<<<dim3(D / 64, Mp / 128), 256, 0, stream>>>(
      factsh, WcT, D, D, nullptr, nullptr, 0, 0, nullptr, nullptr, xc, D, D);
  k_packxrc<<<BT * D / 512, 512, 0, stream>>>(xr, xc, XRC);
  k_buildz<<<BT, 512, 0, stream>>>(factsh, q, za, zb);
  k_gemm_mfma<<<dim3(Ep / 64, Mp / 128), 256, 0, stream>>>(
      za, W1T[0], D, D, zb, W1T[2], D, D, b1, nullptr, part0, E, E);

  // 4) hops
  const float* m_in = q;
  float* mb[2] = {m0, m1};
  for (int i = 0; i < NH; ++i) {
    k_buildz<<<BT, 512, 0, stream>>>(factsh, m_in, za, zb);
    k_gemm_mfma<<<dim3(Ep / 64, Mp / 128), 256, 0, stream>>>(
        za, W1T[1], D, D, zb, W1T[3], D, D, nullptr, part0, att_h, E, E);
    k_score<<<BT, 64, 0, stream>>>(att_h, W2, b2, scores);
    k_softmax<<<B, 128, 0, stream>>>(scores, lengths, att);
    // GRU: per-batch streaming, int8 weights, no cross-block sync
    k_gru<<<B, 1024, 0, stream>>>(XRC, UQ8, smax, br, bc, att, lengths, epb);
    k_hop<<<B, 512, 0, stream>>>(m_in, epb, q,
                                 W_hops + (size_t)i * 3 * D * D, b_hops + (size_t)i * D,
                                 mb[i & 1]);
    m_in = mb[i & 1];
  }
  // 5) output
  k_out<<<B, 256, 0, stream>>>(m_in, q, Wo, bo, (float*)d_out);
}

// Round 14
// 2879.775 us; speedup vs baseline: 1.5960x; 1.3815x over previous
//
#include <hip/hip_runtime.h>

constexpr int B  = 64;
constexpr int T  = 121;
constexpr int E  = 300;
constexpr int Ep = 320;    // E padded to K-chunk multiple
constexpr int H  = 256;
constexpr int G4 = 1024;   // 4*H
constexpr int D  = 512;    // 2*H
constexpr int NH = 3;
constexpr int BT = B * T;  // 7744
constexpr int Mp = 7808;   // 61*128, M padded for 128-row tiles

using short8 = __attribute__((ext_vector_type(8))) short;
using f32x4  = __attribute__((ext_vector_type(4))) float;

__device__ __forceinline__ float sigmoidf(float x) { return 1.0f / (1.0f + __expf(-x)); }
__device__ __forceinline__ float tanhf_fast(float x) {
  float e = __expf(2.0f * x);
  return 1.0f - 2.0f / (e + 1.0f);
}
__device__ __forceinline__ unsigned bf16rne(float x) {
  unsigned u = __float_as_uint(x);
  return (u + 0x7fffu + ((u >> 16) & 1u)) >> 16;
}
__device__ __forceinline__ float bf_lo(unsigned u) { return __uint_as_float(u << 16); }
__device__ __forceinline__ float bf_hi(unsigned u) { return __uint_as_float(u & 0xffff0000u); }
__device__ __forceinline__ float bfu(unsigned short u) { return __uint_as_float(((unsigned)u) << 16); }

#if defined(__has_builtin)
#if __has_builtin(__builtin_amdgcn_sdot4)
#define HAS_SDOT4 1
#endif
#if __has_builtin(__builtin_amdgcn_cvt_f32_ubyte0)
#define HAS_UBYTE 1
#endif
#endif
#ifdef HAS_UBYTE
__device__ __forceinline__ float UB0(unsigned u) { return __builtin_amdgcn_cvt_f32_ubyte0(u); }
__device__ __forceinline__ float UB1(unsigned u) { return __builtin_amdgcn_cvt_f32_ubyte1(u); }
__device__ __forceinline__ float UB2(unsigned u) { return __builtin_amdgcn_cvt_f32_ubyte2(u); }
__device__ __forceinline__ float UB3(unsigned u) { return __builtin_amdgcn_cvt_f32_ubyte3(u); }
#else
__device__ __forceinline__ float UB0(unsigned u) { return (float)(u & 0xffu); }
__device__ __forceinline__ float UB1(unsigned u) { return (float)((u >> 8) & 0xffu); }
__device__ __forceinline__ float UB2(unsigned u) { return (float)((u >> 16) & 0xffu); }
__device__ __forceinline__ float UB3(unsigned u) { return (float)((u >> 24) & 0xffu); }
#endif

// ---------------- weight packing ----------------
// LSTM: bf16 pair-packed, uint4-grouped (round-4 verified)
__global__ void k_pack_lstm(const float* __restrict__ Wh,
                            uint4* __restrict__ PAQ, uint4* __restrict__ PBQ) {
  int idx = blockIdx.x * 256 + threadIdx.x;   // over (H/4)*256 = 16384
  int k4 = idx >> 8, j = idx & 255;
  int k = 4 * k4;
  uint4 a, bq;
  const float* r0 = Wh + (size_t)(k + 0) * G4;
  const float* r1 = Wh + (size_t)(k + 1) * G4;
  const float* r2 = Wh + (size_t)(k + 2) * G4;
  const float* r3 = Wh + (size_t)(k + 3) * G4;
  a.x  = bf16rne(r0[j]) | (bf16rne(r0[j + 256]) << 16);
  a.y  = bf16rne(r1[j]) | (bf16rne(r1[j + 256]) << 16);
  a.z  = bf16rne(r2[j]) | (bf16rne(r2[j + 256]) << 16);
  a.w  = bf16rne(r3[j]) | (bf16rne(r3[j + 256]) << 16);
  bq.x = bf16rne(r0[j + 512]) | (bf16rne(r0[j + 768]) << 16);
  bq.y = bf16rne(r1[j + 512]) | (bf16rne(r1[j + 768]) << 16);
  bq.z = bf16rne(r2[j + 512]) | (bf16rne(r2[j + 768]) << 16);
  bq.w = bf16rne(r3[j + 512]) | (bf16rne(r3[j + 768]) << 16);
  PAQ[idx] = a;
  PBQ[idx] = bq;
}

// generic B^T bf16 pack with zero padding: WT[n*Kpad + k] = bf16(W[k*stride + n]) or 0
__global__ void k_packT(const float* __restrict__ W, unsigned short* __restrict__ WT,
                        int Ksrc, int Nsrc, int stride, int Kpad) {
  int idx = blockIdx.x * 256 + threadIdx.x;
  int n = idx / Kpad, k = idx - n * Kpad;
  float v = (k < Ksrc && n < Nsrc) ? W[(size_t)k * stride + n] : 0.0f;
  WT[idx] = (unsigned short)bf16rne(v);
}

// pack xr/xc (f32) -> bf16 pair, IN PLACE over xr (no restrict: intentional alias)
__global__ void k_packxrc(const float* xr, const float* xc, unsigned* XRC) {
  size_t i = (size_t)blockIdx.x * 512 + threadIdx.x;
  float r = xr[i], c = xc[i];
  XRC[i] = bf16rne(r) | (bf16rne(c) << 16);
}

// absmax of Ur/Uc (uint-bit compare valid for non-negative floats)
__global__ void k_scales(const float* __restrict__ Ur, const float* __restrict__ Uc,
                         unsigned* __restrict__ smax) {
  int i = blockIdx.x * 256 + threadIdx.x;     // over D*D
  unsigned a = __float_as_uint(fabsf(Ur[i]));
  unsigned b = __float_as_uint(fabsf(Uc[i]));
  for (int off = 32; off > 0; off >>= 1) {
    a = max(a, (unsigned)__shfl_xor((int)a, off));
    b = max(b, (unsigned)__shfl_xor((int)b, off));
  }
  if ((threadIdx.x & 63) == 0) {
    atomicMax(&smax[0], a);
    atomicMax(&smax[1], b);
  }
}

#ifdef HAS_SDOT4
// signed 4-byte pack
__device__ __forceinline__ unsigned pk4(float a, float b, float c, float d, float inv) {
  int qa = __float2int_rn(a * inv), qb = __float2int_rn(b * inv);
  int qc = __float2int_rn(c * inv), qd = __float2int_rn(d * inv);
  return (qa & 0xff) | ((qb & 0xff) << 8) | ((qc & 0xff) << 16) | ((qd & 0xff) << 24);
}
// GRU signed-int8 pack, dot4 layout:
// UQ8[k8*D + j] = { r(k..k+3), c(k..k+3), r(k+4..k+7), c(k+4..k+7) } signed bytes
__global__ void k_pack_gru8(const float* __restrict__ Ur, const float* __restrict__ Uc,
                            const unsigned* __restrict__ smax, uint4* __restrict__ UQ8) {
  int idx = blockIdx.x * 256 + threadIdx.x;   // over (D/8)*D = 32768
  int k8 = idx >> 9, j = idx & 511;
  int k0 = k8 * 8;
  float invr = 127.0f / __uint_as_float(smax[0]);
  float invc = 127.0f / __uint_as_float(smax[1]);
  uint4 o;
  o.x = pk4(Ur[(size_t)(k0 + 0) * D + j], Ur[(size_t)(k0 + 1) * D + j],
            Ur[(size_t)(k0 + 2) * D + j], Ur[(size_t)(k0 + 3) * D + j], invr);
  o.y = pk4(Uc[(size_t)(k0 + 0) * D + j], Uc[(size_t)(k0 + 1) * D + j],
            Uc[(size_t)(k0 + 2) * D + j], Uc[(size_t)(k0 + 3) * D + j], invc);
  o.z = pk4(Ur[(size_t)(k0 + 4) * D + j], Ur[(size_t)(k0 + 5) * D + j],
            Ur[(size_t)(k0 + 6) * D + j], Ur[(size_t)(k0 + 7) * D + j], invr);
  o.w = pk4(Uc[(size_t)(k0 + 4) * D + j], Uc[(size_t)(k0 + 5) * D + j],
            Uc[(size_t)(k0 + 6) * D + j], Uc[(size_t)(k0 + 7) * D + j], invc);
  UQ8[idx] = o;
}
#else
// round-13 unsigned pack (zero-point 128), r,c interleaved per k-pair
__global__ void k_pack_gru8(const float* __restrict__ Ur, const float* __restrict__ Uc,
                            const unsigned* __restrict__ smax, uint4* __restrict__ UQ8) {
  int idx = blockIdx.x * 256 + threadIdx.x;
  int k8 = idx >> 9, j = idx & 511;
  float invr = 127.0f / __uint_as_float(smax[0]);
  float invc = 127.0f / __uint_as_float(smax[1]);
  unsigned dw[4];
#pragma unroll
  for (int d = 0; d < 4; ++d) {
    int k0 = k8 * 8 + 2 * d;
    unsigned r0 = (unsigned)(__float2int_rn(Ur[(size_t)k0 * D + j] * invr) + 128);
    unsigned c0 = (unsigned)(__float2int_rn(Uc[(size_t)k0 * D + j] * invc) + 128);
    unsigned r1 = (unsigned)(__float2int_rn(Ur[(size_t)(k0 + 1) * D + j] * invr) + 128);
    unsigned c1 = (unsigned)(__float2int_rn(Uc[(size_t)(k0 + 1) * D + j] * invc) + 128);
    dw[d] = r0 | (c0 << 8) | (r1 << 16) | (c1 << 24);
  }
  UQ8[idx] = make_uint4(dw[0], dw[1], dw[2], dw[3]);
}
#endif

// ---------------- embedding gather -> bf16, K-padded ----------------
__global__ void k_gather(const int* __restrict__ tokens, const float* __restrict__ emb,
                         unsigned short* __restrict__ xh) {
  int bt = blockIdx.x;
  int tok = tokens[bt];
  const float* src = emb + (size_t)tok * E;
  unsigned short* dst = xh + (size_t)bt * Ep;
  for (int e = threadIdx.x; e < Ep; e += 256)
    dst[e] = (e < E) ? (unsigned short)bf16rne(src[e]) : (unsigned short)0;
}

// ---------------- bf16 MFMA GEMM (round-6 verified) ----------------
__global__ __launch_bounds__(256) void k_gemm_mfma(
    const unsigned short* __restrict__ A1, const unsigned short* __restrict__ B1, int K1, int lda1,
    const unsigned short* __restrict__ A2, const unsigned short* __restrict__ B2, int K2, int lda2,
    const float* __restrict__ bias, const float* __restrict__ Cin,
    float* __restrict__ C, int Nreal, int Cstride)
{
  __shared__ unsigned short As[128][40];
  __shared__ unsigned short Bs[64][40];
  int tid = threadIdx.x;
  int l = tid & 63, w = tid >> 6;
  int row0 = blockIdx.y * 128, col0 = blockIdx.x * 64;
  int lrow = l & 15, lk = (l >> 4) * 8, lq = (l >> 4) * 4;
  int ar = tid >> 1, asg = (tid & 1) * 16;
  int br = tid >> 2, bsg = (tid & 3) * 8;
  f32x4 acc[2][4] = {};
#pragma unroll 1
  for (int pass = 0; pass < 2; ++pass) {
    const unsigned short* A  = pass ? A2 : A1;
    const unsigned short* Bt = pass ? B2 : B1;
    int K   = pass ? K2 : K1;
    int lda = pass ? lda2 : lda1;
    if (K == 0) break;
    for (int k0 = 0; k0 < K; k0 += 32) {
      const uint4* ga = (const uint4*)(A + (size_t)(row0 + ar) * lda + k0 + asg);
      uint4 a0 = ga[0], a1 = ga[1];
      uint4 b0 = *(const uint4*)(Bt + (size_t)(col0 + br) * K + k0 + bsg);
      __syncthreads();
      *(uint4*)&As[ar][asg]     = a0;
      *(uint4*)&As[ar][asg + 8] = a1;
      *(uint4*)&Bs[br][bsg]     = b0;
      __syncthreads();
      short8 av[2], bv[4];
#pragma unroll
      for (int f = 0; f < 2; ++f)
        av[f] = *(const short8*)&As[w * 32 + f * 16 + lrow][lk];
#pragma unroll
      for (int fc = 0; fc < 4; ++fc)
        bv[fc] = *(const short8*)&Bs[fc * 16 + lrow][lk];
#pragma unroll
      for (int f = 0; f < 2; ++f)
#pragma unroll
        for (int fc = 0; fc < 4; ++fc)
          acc[f][fc] = __builtin_amdgcn_mfma_f32_16x16x32_bf16(av[f], bv[fc], acc[f][fc], 0, 0, 0);
    }
  }
#pragma unroll
  for (int f = 0; f < 2; ++f) {
#pragma unroll
    for (int fc = 0; fc < 4; ++fc) {
      int c = col0 + fc * 16 + lrow;
      if (c < Nreal) {
        float bb = bias ? bias[c] : 0.0f;
#pragma unroll
        for (int i = 0; i < 4; ++i) {
          int r = row0 + w * 32 + f * 16 + lq + i;
          if (r < BT) {
            float v = acc[f][fc][i] + bb;
            if (Cin) v += Cin[(size_t)r * Cstride + c];
            C[(size_t)r * Cstride + c] = v;
          }
        }
      }
    }
  }
}

// ---------------- BiLSTM scan (round-6 verified) ----------------
__global__ __launch_bounds__(512) void k_lstm(
    const float* __restrict__ xp_f, const float* __restrict__ xp_b,
    const uint4* __restrict__ PAQ_f, const uint4* __restrict__ PBQ_f,
    const uint4* __restrict__ PAQ_b, const uint4* __restrict__ PBQ_b,
    const int* __restrict__ lengths, unsigned short* __restrict__ factsh)
{
  int b = blockIdx.x;
  int dir = blockIdx.y;
  const float* xp = dir ? xp_b : xp_f;
  const uint4* PAQ = dir ? PAQ_b : PAQ_f;
  const uint4* PBQ = dir ? PBQ_b : PBQ_f;
  int tid = threadIdx.x;
  int j = tid & 255, half = tid >> 8;
  __shared__ float hs[H];
  __shared__ float4 red[512];
  hs[j] = 0.0f;
  float c = 0.0f, h = 0.0f;
  int nsteps = dir ? T : lengths[b];
  const uint4* pa = PAQ + (size_t)(half * 32) * 256 + j;
  const uint4* pb = PBQ + (size_t)(half * 32) * 256 + j;
  const float4* hs4 = reinterpret_cast<const float4*>(hs) + half * 32;
  __syncthreads();
  for (int s = 0; s < nsteps; ++s) {
    int t = dir ? (T - 1 - s) : s;
    float g0 = 0.f, g1 = 0.f, g2 = 0.f, g3 = 0.f;
#pragma unroll 4
    for (int k4 = 0; k4 < 32; ++k4) {
      uint4 a  = pa[(size_t)k4 * 256];
      uint4 bq = pb[(size_t)k4 * 256];
      float4 hv = hs4[k4];
      g0 = fmaf(hv.x, bf_lo(a.x), g0);  g1 = fmaf(hv.x, bf_hi(a.x), g1);
      g2 = fmaf(hv.x, bf_lo(bq.x), g2); g3 = fmaf(hv.x, bf_hi(bq.x), g3);
      g0 = fmaf(hv.y, bf_lo(a.y), g0);  g1 = fmaf(hv.y, bf_hi(a.y), g1);
      g2 = fmaf(hv.y, bf_lo(bq.y), g2); g3 = fmaf(hv.y, bf_hi(bq.y), g3);
      g0 = fmaf(hv.z, bf_lo(a.z), g0);  g1 = fmaf(hv.z, bf_hi(a.z), g1);
      g2 = fmaf(hv.z, bf_lo(bq.z), g2); g3 = fmaf(hv.z, bf_hi(bq.z), g3);
      g0 = fmaf(hv.w, bf_lo(a.w), g0);  g1 = fmaf(hv.w, bf_hi(a.w), g1);
      g2 = fmaf(hv.w, bf_lo(bq.w), g2); g3 = fmaf(hv.w, bf_hi(bq.w), g3);
    }
    red[tid] = make_float4(g0, g1, g2, g3);
    __syncthreads();
    if (half == 0) {
      float4 o = red[tid + 256];
      const float* xrow = xp + (size_t)(b * T + t) * G4;
      g0 += o.x + xrow[j];
      g1 += o.y + xrow[j + 256];
      g2 += o.z + xrow[j + 512];
      g3 += o.w + xrow[j + 768];
      float ig = sigmoidf(g0);
      float fg = sigmoidf(g1);
      float gg = tanhf_fast(g2);
      float og = sigmoidf(g3);
      c = fg * c + ig * gg;
      h = og * tanhf_fast(c);
      hs[j] = h;
      factsh[(size_t)(b * T + t) * D + dir * H + j] = (unsigned short)bf16rne(h);
    }
    __syncthreads();
  }
}

// ---------------- z halves -> bf16 ----------------
__global__ void k_buildz(const unsigned short* __restrict__ factsh, const float* __restrict__ v,
                         unsigned short* __restrict__ za, unsigned short* __restrict__ zb) {
  int bt = blockIdx.x;
  int b = bt / T;
  int d = threadIdx.x;  // 512
  float f = bfu(factsh[(size_t)bt * D + d]);
  float vv = v[(size_t)b * D + d];
  za[(size_t)bt * D + d] = (unsigned short)bf16rne(f * vv);
  zb[(size_t)bt * D + d] = (unsigned short)bf16rne(fabsf(f - vv));
}

// ---------------- score ----------------
__global__ void k_score(const float* __restrict__ att_h, const float* __restrict__ W2,
                        const float* __restrict__ b2, float* __restrict__ s) {
  int bt = blockIdx.x;
  int tid = threadIdx.x;  // 64
  float acc = 0.f;
  for (int e = tid; e < E; e += 64)
    acc += tanhf_fast(att_h[(size_t)bt * E + e]) * W2[e];
  for (int off = 32; off > 0; off >>= 1) acc += __shfl_down(acc, off);
  if (tid == 0) s[bt] = acc + b2[0];
}

// ---------------- masked softmax ----------------
__global__ void k_softmax(const float* __restrict__ s, const int* __restrict__ lengths,
                          float* __restrict__ a) {
  int b = blockIdx.x;
  int t = threadIdx.x;  // 128
  int len = lengths[b];
  __shared__ float wred[2];
  float val = -1e30f;
  if (t < T) val = (t < len) ? s[b * T + t] : -1e9f;
  float mx = val;
  for (int off = 32; off > 0; off >>= 1) mx = fmaxf(mx, __shfl_xor(mx, off));
  int wid = t >> 6, lane = t & 63;
  if (lane == 0) wred[wid] = mx;
  __syncthreads();
  mx = fmaxf(wred[0], wred[1]);
  __syncthreads();
  float e = (t < T && t < len) ? __expf(val - mx) : 0.0f;
  float sum = e;
  for (int off = 32; off > 0; off >>= 1) sum += __shfl_xor(sum, off);
  if (lane == 0) wred[wid] = sum;
  __syncthreads();
  float tot = wred[0] + wred[1];
  if (t < T) a[b * T + t] = e / tot;
}

// ---------------- zero helper ----------------
__global__ void k_zero(int* __restrict__ p, int n) {
  int i = blockIdx.x * blockDim.x + threadIdx.x;
  if (i < n) p[i] = 0;
}

// ---------------- attention GRU: per-batch streaming, int8 dot4 ----------------
#ifdef HAS_SDOT4
// One block (1024 thr) per batch, no cross-block sync. tid&511 = column j,
// tid>>9 = k-half. Weights signed i8 (scale A/127), h quantized to signed i8
// (scale 1/127, valid since |h|<=1 by convexity). 4 MACs per sdot4 -> ~8x less
// VALU than fma+cvt. hq lives in 512B LDS; wave-uniform dword reads broadcast.
__global__ __launch_bounds__(1024) void k_gru(
    const unsigned* __restrict__ XRC, const uint4* __restrict__ UQ8,
    const unsigned* __restrict__ smax,
    const float* __restrict__ br, const float* __restrict__ bc,
    const float* __restrict__ att, const int* __restrict__ lengths,
    float* __restrict__ ep)
{
  int b = blockIdx.x;
  int tid = threadIdx.x;
  int j = tid & 511, half = tid >> 9;
  __shared__ int hqs[D / 4];       // packed i8 h, 512 B
  __shared__ int2 red2[1024];      // 8 KB
  if (tid < D / 4) hqs[tid] = 0;
  float hj = 0.0f;
  int len = lengths[b];
  float sAr = __uint_as_float(smax[0]) * (1.0f / 16129.0f);  // A_r/(127*127)
  float sAc = __uint_as_float(smax[1]) * (1.0f / 16129.0f);
  float brj = br[j], bcj = bc[j];
  const uint4* up = UQ8 + (size_t)(half * 32) * 512 + j;
  __syncthreads();
  for (int t = 0; t < len; ++t) {
    float g = att[b * T + t];
    unsigned xq = XRC[(size_t)(b * T + t) * D + j];
    int ar = 0, ac = 0;
#pragma unroll 8
    for (int k8 = 0; k8 < 32; ++k8) {
      uint4 u = up[(size_t)k8 * 512];
      int h0 = hqs[(half * 32 + k8) * 2];
      int h1 = hqs[(half * 32 + k8) * 2 + 1];
      ar = __builtin_amdgcn_sdot4(h0, (int)u.x, ar, false);
      ac = __builtin_amdgcn_sdot4(h0, (int)u.y, ac, false);
      ar = __builtin_amdgcn_sdot4(h1, (int)u.z, ar, false);
      ac = __builtin_amdgcn_sdot4(h1, (int)u.w, ac, false);
    }
    red2[tid] = make_int2(ar, ac);
    __syncthreads();
    if (half == 0) {
      int2 o = red2[tid + 512];
      float racc = sAr * (float)(ar + o.x);
      float cacc = sAc * (float)(ac + o.y);
      float r  = sigmoidf(bf_lo(xq) + racc + brj);
      float hc = tanhf_fast(bf_hi(xq) + r * cacc + bcj);
      hj = g * hc + (1.f - g) * hj;
      int qi = __float2int_rn(hj * 127.0f);
      ((signed char*)hqs)[j] = (signed char)qi;
    }
    __syncthreads();
  }
  if (half == 0) ep[(size_t)b * D + j] = hj;
}
#else
// fallback: round-13 unsigned-int8 fma kernel (verified)
__global__ __launch_bounds__(1024) void k_gru(
    const unsigned* __restrict__ XRC, const uint4* __restrict__ UQ8,
    const unsigned* __restrict__ smax,
    const float* __restrict__ br, const float* __restrict__ bc,
    const float* __restrict__ att, const int* __restrict__ lengths,
    float* __restrict__ ep)
{
  int b = blockIdx.x;
  int tid = threadIdx.x;
  int j = tid & 511, half = tid >> 9;
  __shared__ float hs[D];
  __shared__ float2 red[1024];
  __shared__ float hsL;
  if (half == 0) hs[j] = 0.0f;
  if (tid == 0) hsL = 0.0f;
  float hj = 0.0f;
  int len = lengths[b];
  float s_r = __uint_as_float(smax[0]) * (1.0f / 127.0f);
  float s_c = __uint_as_float(smax[1]) * (1.0f / 127.0f);
  float brj = br[j], bcj = bc[j];
  const uint4* up = UQ8 + (size_t)(half * 32) * 512 + j;
  const float4* hs4 = reinterpret_cast<const float4*>(hs);
  __syncthreads();
  for (int t = 0; t < len; ++t) {
    float g = att[b * T + t];
    unsigned xq = XRC[(size_t)(b * T + t) * D + j];
    float qr = 0.f, qc = 0.f;
#pragma unroll 8
    for (int k8 = 0; k8 < 32; ++k8) {
      uint4 u = up[(size_t)k8 * 512];
      float4 h0 = hs4[(half * 32 + k8) * 2];
      float4 h1 = hs4[(half * 32 + k8) * 2 + 1];
      qr = fmaf(h0.x, UB0(u.x), qr); qc = fmaf(h0.x, UB1(u.x), qc);
      qr = fmaf(h0.y, UB2(u.x), qr); qc = fmaf(h0.y, UB3(u.x), qc);
      qr = fmaf(h0.z, UB0(u.y), qr); qc = fmaf(h0.z, UB1(u.y), qc);
      qr = fmaf(h0.w, UB2(u.y), qr); qc = fmaf(h0.w, UB3(u.y), qc);
      qr = fmaf(h1.x, UB0(u.z), qr); qc = fmaf(h1.x, UB1(u.z), qc);
      qr = fmaf(h1.y, UB2(u.z), qr); qc = fmaf(h1.y, UB3(u.z), qc);
      qr = fmaf(h1.z, UB0(u.w), qr); qc = fmaf(h1.z, UB1(u.w), qc);
      qr = fmaf(h1.w, UB2(u.w), qr); qc = fmaf(h1.w, UB3(u.w), qc);
    }
    red[tid] = make_float2(qr, qc);
    __syncthreads();
    if (half == 0) {
      float2 o = red[tid + 512];
      float hsum = hsL;
      float racc = s_r * (qr + o.x - 128.0f * hsum);
      float cacc = s_c * (qc + o.y - 128.0f * hsum);
      float r  = sigmoidf(bf_lo(xq) + racc + brj);
      float hc = tanhf_fast(bf_hi(xq) + r * cacc + bcj);
      hj = g * hc + (1.f - g) * hj;
      hs[j] = hj;
    }
    __syncthreads();
    if (tid < 64) {
      float4 a = hs4[2 * tid], bq = hs4[2 * tid + 1];
      float s4 = ((a.x + a.y) + (a.z + a.w)) + ((bq.x + bq.y) + (bq.z + bq.w));
      for (int off = 32; off > 0; off >>= 1) s4 += __shfl_down(s4, off);
      if (tid == 0) hsL = s4;
    }
  }
  if (half == 0) ep[(size_t)b * D + j] = hj;
}
#endif

// ---------------- hop projection ----------------
__global__ __launch_bounds__(512) void k_hop(
    const float* __restrict__ m_in, const float* __restrict__ ep,
    const float* __restrict__ q, const float* __restrict__ Whop,
    const float* __restrict__ bhop, float* __restrict__ m_out)
{
  int b = blockIdx.x, j = threadIdx.x;
  __shared__ float av[3 * D];
  av[j]         = m_in[(size_t)b * D + j];
  av[D + j]     = ep[(size_t)b * D + j];
  av[2 * D + j] = q[(size_t)b * D + j];
  __syncthreads();
  float acc = bhop[j];
#pragma unroll 4
  for (int k = 0; k < 3 * D; ++k)
    acc = fmaf(av[k], Whop[(size_t)k * D + j], acc);
  m_out[(size_t)b * D + j] = fmaxf(acc, 0.0f);
}

// ---------------- output ----------------
__global__ void k_out(const float* __restrict__ m, const float* __restrict__ q,
                      const float* __restrict__ Wo, const float* __restrict__ bo,
                      float* __restrict__ out)
{
  int b = blockIdx.x, tid = threadIdx.x;  // 256
  float acc = 0.f;
  for (int k = tid; k < D; k += 256)
    acc += m[(size_t)b * D + k] * Wo[k] + q[(size_t)b * D + k] * Wo[D + k];
  for (int off = 32; off > 0; off >>= 1) acc += __shfl_down(acc, off);
  __shared__ float red[4];
  int wid = tid >> 6, lane = tid & 63;
  if (lane == 0) red[wid] = acc;
  __syncthreads();
  if (tid == 0) {
    float tot = red[0] + red[1] + red[2] + red[3];
    out[b] = 1.0f / (1.0f + __expf(-(tot + bo[0])));
  }
}

extern "C" void kernel_launch(void* const* d_in, const int* in_sizes, int n_in,
                              void* d_out, int out_size, void* d_ws, size_t ws_size,
                              hipStream_t stream)
{
  const int*   tokens  = (const int*)d_in[0];
  const int*   lengths = (const int*)d_in[1];
  const float* emb     = (const float*)d_in[2];
  const float* Wx_f    = (const float*)d_in[3];
  const float* Wh_f    = (const float*)d_in[4];
  const float* b_f     = (const float*)d_in[5];
  const float* Wx_b    = (const float*)d_in[6];
  const float* Wh_b    = (const float*)d_in[7];
  const float* b_b     = (const float*)d_in[8];
  const float* W1      = (const float*)d_in[9];
  const float* b1      = (const float*)d_in[10];
  const float* W2      = (const float*)d_in[11];
  const float* b2      = (const float*)d_in[12];
  const float* Wr      = (const float*)d_in[13];
  const float* Ur      = (const float*)d_in[14];
  const float* br      = (const float*)d_in[15];
  const float* Wc      = (const float*)d_in[16];
  const float* Uc      = (const float*)d_in[17];
  const float* bc      = (const float*)d_in[18];
  const float* q       = (const float*)d_in[19];
  const float* W_hops  = (const float*)d_in[20];
  const float* b_hops  = (const float*)d_in[21];
  const float* Wo      = (const float*)d_in[22];
  const float* bo      = (const float*)d_in[23];
  float* ws = (float*)d_ws;

  // ---- workspace layout ----
  float* p = ws;
  unsigned short* xh = (unsigned short*)p;  p += (size_t)Mp * Ep / 2;
  float* xp_f   = p;  p += (size_t)BT * G4;                                 // later: xr | xc -> XRC
  float* xp_b   = p;  p += (size_t)BT * G4;                                 // later: za | zb
  unsigned short* factsh = (unsigned short*)p;  p += (size_t)Mp * D / 2;
  float* att_h  = p;  p += (size_t)BT * E;
  float* part0  = p;  p += (size_t)BT * E;
  float* scores = p;  p += BT;
  float* att    = p;  p += BT;
  float* m0     = p;  p += (size_t)B * D;
  float* m1     = p;  p += (size_t)B * D;
  float* epb    = p;  p += (size_t)B * D;
  unsigned* smax = (unsigned*)p;  p += 4;
  uint4* UQ8    = (uint4*)p;  p += (size_t)(D / 8) * D * 4;                 // 512KB int8 GRU weights
  uint4* PAQ_f  = (uint4*)p;  p += (size_t)(H / 4) * 256 * 4;
  uint4* PBQ_f  = (uint4*)p;  p += (size_t)(H / 4) * 256 * 4;
  uint4* PAQ_b  = (uint4*)p;  p += (size_t)(H / 4) * 256 * 4;
  uint4* PBQ_b  = (uint4*)p;  p += (size_t)(H / 4) * 256 * 4;
  unsigned short* WxT_f = (unsigned short*)p;  p += (size_t)G4 * Ep / 2;
  unsigned short* WxT_b = (unsigned short*)p;  p += (size_t)G4 * Ep / 2;
  unsigned short* WrT   = (unsigned short*)p;  p += (size_t)D * D / 2;
  unsigned short* WcT   = (unsigned short*)p;  p += (size_t)D * D / 2;
  unsigned short* W1T[4];
  for (int c = 0; c < 4; ++c) { W1T[c] = (unsigned short*)p; p += (size_t)Ep * D / 2; }
  float* xr = xp_f;
  float* xc = xp_f + (size_t)BT * D;
  unsigned* XRC = (unsigned*)xr;               // in-place bf16-pair pack over xr
  unsigned short* za = (unsigned short*)xp_b;
  unsigned short* zb = (unsigned short*)xp_b + (size_t)Mp * D;

  // 0) scales + pack weights (GRU int8; LSTM bf16; GEMM weights bf16^T)
  k_zero<<<1, 64, 0, stream>>>((int*)smax, 4);
  k_scales<<<D * D / 256, 256, 0, stream>>>(Ur, Uc, smax);
  k_pack_gru8<<<(D / 8) * D / 256, 256, 0, stream>>>(Ur, Uc, smax, UQ8);
  k_pack_lstm<<<(H / 4) * 256 / 256, 256, 0, stream>>>(Wh_f, PAQ_f, PBQ_f);
  k_pack_lstm<<<(H / 4) * 256 / 256, 256, 0, stream>>>(Wh_b, PAQ_b, PBQ_b);
  k_packT<<<G4 * Ep / 256, 256, 0, stream>>>(Wx_f, WxT_f, E, G4, G4, Ep);
  k_packT<<<G4 * Ep / 256, 256, 0, stream>>>(Wx_b, WxT_b, E, G4, G4, Ep);
  k_packT<<<D * D / 256, 256, 0, stream>>>(Wr, WrT, D, D, D, D);
  k_packT<<<D * D / 256, 256, 0, stream>>>(Wc, WcT, D, D, D, D);
  for (int c = 0; c < 4; ++c)
    k_packT<<<Ep * D / 256, 256, 0, stream>>>(W1 + (size_t)c * D * E, W1T[c], D, E, E, D);

  // 1) embed + input projections (MFMA)
  k_gather<<<BT, 256, 0, stream>>>(tokens, emb, xh);
  k_gemm_mfma<<<dim3(G4 / 64, Mp / 128), 256, 0, stream>>>(
      xh, WxT_f, Ep, Ep, nullptr, nullptr, 0, 0, b_f, nullptr, xp_f, G4, G4);
  k_gemm_mfma<<<dim3(G4 / 64, Mp / 128), 256, 0, stream>>>(
      xh, WxT_b, Ep, Ep, nullptr, nullptr, 0, 0, b_b, nullptr, xp_b, G4, G4);
  // 2) BiLSTM
  k_lstm<<<dim3(B, 2), 512, 0, stream>>>(xp_f, xp_b, PAQ_f, PBQ_f, PAQ_b, PBQ_b, lengths, factsh);
  // 3) hop-invariant precomputes (MFMA); then pack xr/xc -> bf16 pairs in place
  k_gemm_mfma<<<dim3(D / 64, Mp / 128), 256, 0, stream>>>(
      factsh, WrT, D, D, nullptr, nullptr, 0, 0, nullptr, nullptr, xr, D, D);
  k_gemm_mfma<<<dim3(D / 64, Mp / 128), 256, 0, stream>>>(
      factsh, WcT, D, D, nullptr, nullptr, 0, 0, nullptr, nullptr, xc, D, D);
  k_packxrc<<<BT * D / 512, 512, 0, stream>>>(xr, xc, XRC);
  k_buildz<<<BT, 512, 0, stream>>>(factsh, q, za, zb);
  k_gemm_mfma<<<dim3(Ep / 64, Mp / 128), 256, 0, stream>>>(
      za, W1T[0], D, D, zb, W1T[2], D, D, b1, nullptr, part0, E, E);

  // 4) hops
  const float* m_in = q;
  float* mb[2] = {m0, m1};
  for (int i = 0; i < NH; ++i) {
    k_buildz<<<BT, 512, 0, stream>>>(factsh, m_in, za, zb);
    k_gemm_mfma<<<dim3(Ep / 64, Mp / 128), 256, 0, stream>>>(
        za, W1T[1], D, D, zb, W1T[3], D, D, nullptr, part0, att_h, E, E);
    k_score<<<BT, 64, 0, stream>>>(att_h, W2, b2, scores);
    k_softmax<<<B, 128, 0, stream>>>(scores, lengths, att);
    // GRU: per-batch streaming, signed-int8 dot4, no cross-block sync
    k_gru<<<B, 1024, 0, stream>>>(XRC, UQ8, smax, br, bc, att, lengths, epb);
    k_hop<<<B, 512, 0, stream>>>(m_in, epb, q,
                                 W_hops + (size_t)i * 3 * D * D, b_hops + (size_t)i * D,
                                 mb[i & 1]);
    m_in = mb[i & 1];
  }
  // 5) output
  k_out<<<B, 256, 0, stream>>>(m_in, q, Wo, bo, (float*)d_out);
}

// Round 17
// 2802.727 us; speedup vs baseline: 1.6399x; 1.0275x over previous
//
#include <hip/hip_runtime.h>

constexpr int B  = 64;
constexpr int T  = 121;
constexpr int E  = 300;
constexpr int Ep = 320;    // E padded to K-chunk multiple
constexpr int H  = 256;
constexpr int G4 = 1024;   // 4*H
constexpr int D  = 512;    // 2*H
constexpr int NH = 3;
constexpr int BT = B * T;  // 7744
constexpr int Mp = 7808;   // 61*128, M padded for 128-row tiles

using short8 = __attribute__((ext_vector_type(8))) short;
using f32x4  = __attribute__((ext_vector_type(4))) float;

__device__ __forceinline__ float sigmoidf(float x) { return 1.0f / (1.0f + __expf(-x)); }
__device__ __forceinline__ float tanhf_fast(float x) {
  float e = __expf(2.0f * x);
  return 1.0f - 2.0f / (e + 1.0f);
}
__device__ __forceinline__ unsigned bf16rne(float x) {
  unsigned u = __float_as_uint(x);
  return (u + 0x7fffu + ((u >> 16) & 1u)) >> 16;
}
__device__ __forceinline__ float bf_lo(unsigned u) { return __uint_as_float(u << 16); }
__device__ __forceinline__ float bf_hi(unsigned u) { return __uint_as_float(u & 0xffff0000u); }
__device__ __forceinline__ float bfu(unsigned short u) { return __uint_as_float(((unsigned)u) << 16); }

#if defined(__has_builtin)
#if __has_builtin(__builtin_amdgcn_sdot4)
#define HAS_SDOT4 1
#endif
#if __has_builtin(__builtin_amdgcn_cvt_f32_ubyte0)
#define HAS_UBYTE 1
#endif
#endif
#ifdef HAS_UBYTE
__device__ __forceinline__ float UB0(unsigned u) { return __builtin_amdgcn_cvt_f32_ubyte0(u); }
__device__ __forceinline__ float UB1(unsigned u) { return __builtin_amdgcn_cvt_f32_ubyte1(u); }
__device__ __forceinline__ float UB2(unsigned u) { return __builtin_amdgcn_cvt_f32_ubyte2(u); }
__device__ __forceinline__ float UB3(unsigned u) { return __builtin_amdgcn_cvt_f32_ubyte3(u); }
#else
__device__ __forceinline__ float UB0(unsigned u) { return (float)(u & 0xffu); }
__device__ __forceinline__ float UB1(unsigned u) { return (float)((u >> 8) & 0xffu); }
__device__ __forceinline__ float UB2(unsigned u) { return (float)((u >> 16) & 0xffu); }
__device__ __forceinline__ float UB3(unsigned u) { return (float)((u >> 24) & 0xffu); }
#endif

// ---------------- weight packing ----------------
// LSTM: bf16 pair-packed, uint4-grouped (round-4 verified)
__global__ void k_pack_lstm(const float* __restrict__ Wh,
                            uint4* __restrict__ PAQ, uint4* __restrict__ PBQ) {
  int idx = blockIdx.x * 256 + threadIdx.x;   // over (H/4)*256 = 16384
  int k4 = idx >> 8, j = idx & 255;
  int k = 4 * k4;
  uint4 a, bq;
  const float* r0 = Wh + (size_t)(k + 0) * G4;
  const float* r1 = Wh + (size_t)(k + 1) * G4;
  const float* r2 = Wh + (size_t)(k + 2) * G4;
  const float* r3 = Wh + (size_t)(k + 3) * G4;
  a.x  = bf16rne(r0[j]) | (bf16rne(r0[j + 256]) << 16);
  a.y  = bf16rne(r1[j]) | (bf16rne(r1[j + 256]) << 16);
  a.z  = bf16rne(r2[j]) | (bf16rne(r2[j + 256]) << 16);
  a.w  = bf16rne(r3[j]) | (bf16rne(r3[j + 256]) << 16);
  bq.x = bf16rne(r0[j + 512]) | (bf16rne(r0[j + 768]) << 16);
  bq.y = bf16rne(r1[j + 512]) | (bf16rne(r1[j + 768]) << 16);
  bq.z = bf16rne(r2[j + 512]) | (bf16rne(r2[j + 768]) << 16);
  bq.w = bf16rne(r3[j + 512]) | (bf16rne(r3[j + 768]) << 16);
  PAQ[idx] = a;
  PBQ[idx] = bq;
}

// generic B^T bf16 pack with zero padding
__global__ void k_packT(const float* __restrict__ W, unsigned short* __restrict__ WT,
                        int Ksrc, int Nsrc, int stride, int Kpad) {
  int idx = blockIdx.x * 256 + threadIdx.x;
  int n = idx / Kpad, k = idx - n * Kpad;
  float v = (k < Ksrc && n < Nsrc) ? W[(size_t)k * stride + n] : 0.0f;
  WT[idx] = (unsigned short)bf16rne(v);
}

// pack xr/xc (f32) -> bf16 pair, IN PLACE over xr (no restrict: intentional alias)
__global__ void k_packxrc(const float* xr, const float* xc, unsigned* XRC) {
  size_t i = (size_t)blockIdx.x * 512 + threadIdx.x;
  float r = xr[i], c = xc[i];
  XRC[i] = bf16rne(r) | (bf16rne(c) << 16);
}

// absmax of Ur/Uc (uint-bit compare valid for non-negative floats)
__global__ void k_scales(const float* __restrict__ Ur, const float* __restrict__ Uc,
                         unsigned* __restrict__ smax) {
  int i = blockIdx.x * 256 + threadIdx.x;     // over D*D
  unsigned a = __float_as_uint(fabsf(Ur[i]));
  unsigned b = __float_as_uint(fabsf(Uc[i]));
  for (int off = 32; off > 0; off >>= 1) {
    a = max(a, (unsigned)__shfl_xor((int)a, off));
    b = max(b, (unsigned)__shfl_xor((int)b, off));
  }
  if ((threadIdx.x & 63) == 0) {
    atomicMax(&smax[0], a);
    atomicMax(&smax[1], b);
  }
}

#ifdef HAS_SDOT4
// signed 4-byte pack
__device__ __forceinline__ unsigned pk4(float a, float b, float c, float d, float inv) {
  int qa = __float2int_rn(a * inv), qb = __float2int_rn(b * inv);
  int qc = __float2int_rn(c * inv), qd = __float2int_rn(d * inv);
  return (qa & 0xff) | ((qb & 0xff) << 8) | ((qc & 0xff) << 16) | ((qd & 0xff) << 24);
}
// GRU signed-int8 pack, dot4 layout (round-14 verified)
__global__ void k_pack_gru8(const float* __restrict__ Ur, const float* __restrict__ Uc,
                            const unsigned* __restrict__ smax, uint4* __restrict__ UQ8) {
  int idx = blockIdx.x * 256 + threadIdx.x;   // over (D/8)*D = 32768
  int k8 = idx >> 9, j = idx & 511;
  int k0 = k8 * 8;
  float invr = 127.0f / __uint_as_float(smax[0]);
  float invc = 127.0f / __uint_as_float(smax[1]);
  uint4 o;
  o.x = pk4(Ur[(size_t)(k0 + 0) * D + j], Ur[(size_t)(k0 + 1) * D + j],
            Ur[(size_t)(k0 + 2) * D + j], Ur[(size_t)(k0 + 3) * D + j], invr);
  o.y = pk4(Uc[(size_t)(k0 + 0) * D + j], Uc[(size_t)(k0 + 1) * D + j],
            Uc[(size_t)(k0 + 2) * D + j], Uc[(size_t)(k0 + 3) * D + j], invc);
  o.z = pk4(Ur[(size_t)(k0 + 4) * D + j], Ur[(size_t)(k0 + 5) * D + j],
            Ur[(size_t)(k0 + 6) * D + j], Ur[(size_t)(k0 + 7) * D + j], invr);
  o.w = pk4(Uc[(size_t)(k0 + 4) * D + j], Uc[(size_t)(k0 + 5) * D + j],
            Uc[(size_t)(k0 + 6) * D + j], Uc[(size_t)(k0 + 7) * D + j], invc);
  UQ8[idx] = o;
}
#else
// round-13 unsigned pack (zero-point 128), r,c interleaved per k-pair
__global__ void k_pack_gru8(const float* __restrict__ Ur, const float* __restrict__ Uc,
                            const unsigned* __restrict__ smax, uint4* __restrict__ UQ8) {
  int idx = blockIdx.x * 256 + threadIdx.x;
  int k8 = idx >> 9, j = idx & 511;
  float invr = 127.0f / __uint_as_float(smax[0]);
  float invc = 127.0f / __uint_as_float(smax[1]);
  unsigned dw[4];
#pragma unroll
  for (int d = 0; d < 4; ++d) {
    int k0 = k8 * 8 + 2 * d;
    unsigned r0 = (unsigned)(__float2int_rn(Ur[(size_t)k0 * D + j] * invr) + 128);
    unsigned c0 = (unsigned)(__float2int_rn(Uc[(size_t)k0 * D + j] * invc) + 128);
    unsigned r1 = (unsigned)(__float2int_rn(Ur[(size_t)(k0 + 1) * D + j] * invr) + 128);
    unsigned c1 = (unsigned)(__float2int_rn(Uc[(size_t)(k0 + 1) * D + j] * invc) + 128);
    dw[d] = r0 | (c0 << 8) | (r1 << 16) | (c1 << 24);
  }
  UQ8[idx] = make_uint4(dw[0], dw[1], dw[2], dw[3]);
}
#endif

// ---------------- embedding gather -> bf16, K-padded ----------------
__global__ void k_gather(const int* __restrict__ tokens, const float* __restrict__ emb,
                         unsigned short* __restrict__ xh) {
  int bt = blockIdx.x;
  int tok = tokens[bt];
  const float* src = emb + (size_t)tok * E;
  unsigned short* dst = xh + (size_t)bt * Ep;
  for (int e = threadIdx.x; e < Ep; e += 256)
    dst[e] = (e < E) ? (unsigned short)bf16rne(src[e]) : (unsigned short)0;
}

// ---------------- bf16 MFMA GEMM (round-6 verified) ----------------
__global__ __launch_bounds__(256) void k_gemm_mfma(
    const unsigned short* __restrict__ A1, const unsigned short* __restrict__ B1, int K1, int lda1,
    const unsigned short* __restrict__ A2, const unsigned short* __restrict__ B2, int K2, int lda2,
    const float* __restrict__ bias, const float* __restrict__ Cin,
    float* __restrict__ C, int Nreal, int Cstride)
{
  __shared__ unsigned short As[128][40];
  __shared__ unsigned short Bs[64][40];
  int tid = threadIdx.x;
  int l = tid & 63, w = tid >> 6;
  int row0 = blockIdx.y * 128, col0 = blockIdx.x * 64;
  int lrow = l & 15, lk = (l >> 4) * 8, lq = (l >> 4) * 4;
  int ar = tid >> 1, asg = (tid & 1) * 16;
  int br = tid >> 2, bsg = (tid & 3) * 8;
  f32x4 acc[2][4] = {};
#pragma unroll 1
  for (int pass = 0; pass < 2; ++pass) {
    const unsigned short* A  = pass ? A2 : A1;
    const unsigned short* Bt = pass ? B2 : B1;
    int K   = pass ? K2 : K1;
    int lda = pass ? lda2 : lda1;
    if (K == 0) break;
    for (int k0 = 0; k0 < K; k0 += 32) {
      const uint4* ga = (const uint4*)(A + (size_t)(row0 + ar) * lda + k0 + asg);
      uint4 a0 = ga[0], a1 = ga[1];
      uint4 b0 = *(const uint4*)(Bt + (size_t)(col0 + br) * K + k0 + bsg);
      __syncthreads();
      *(uint4*)&As[ar][asg]     = a0;
      *(uint4*)&As[ar][asg + 8] = a1;
      *(uint4*)&Bs[br][bsg]     = b0;
      __syncthreads();
      short8 av[2], bv[4];
#pragma unroll
      for (int f = 0; f < 2; ++f)
        av[f] = *(const short8*)&As[w * 32 + f * 16 + lrow][lk];
#pragma unroll
      for (int fc = 0; fc < 4; ++fc)
        bv[fc] = *(const short8*)&Bs[fc * 16 + lrow][lk];
#pragma unroll
      for (int f = 0; f < 2; ++f)
#pragma unroll
        for (int fc = 0; fc < 4; ++fc)
          acc[f][fc] = __builtin_amdgcn_mfma_f32_16x16x32_bf16(av[f], bv[fc], acc[f][fc], 0, 0, 0);
    }
  }
#pragma unroll
  for (int f = 0; f < 2; ++f) {
#pragma unroll
    for (int fc = 0; fc < 4; ++fc) {
      int c = col0 + fc * 16 + lrow;
      if (c < Nreal) {
        float bb = bias ? bias[c] : 0.0f;
#pragma unroll
        for (int i = 0; i < 4; ++i) {
          int r = row0 + w * 32 + f * 16 + lq + i;
          if (r < BT) {
            float v = acc[f][fc][i] + bb;
            if (Cin) v += Cin[(size_t)r * Cstride + c];
            C[(size_t)r * Cstride + c] = v;
          }
        }
      }
    }
  }
}

// ---------------- BiLSTM scan: bf16 weights (round-14 verified math), now 1024 thr --
// 4-way k-split (quarters of the 256 k range) -> 16 waves/block for deeper MLP.
__global__ __launch_bounds__(1024) void k_lstm(
    const float* __restrict__ xp_f, const float* __restrict__ xp_b,
    const uint4* __restrict__ PAQ_f, const uint4* __restrict__ PBQ_f,
    const uint4* __restrict__ PAQ_b, const uint4* __restrict__ PBQ_b,
    const int* __restrict__ lengths, unsigned short* __restrict__ factsh)
{
  int b = blockIdx.x;
  int dir = blockIdx.y;
  const float* xp = dir ? xp_b : xp_f;
  const uint4* PAQ = dir ? PAQ_b : PAQ_f;
  const uint4* PBQ = dir ? PBQ_b : PBQ_f;
  int tid = threadIdx.x;
  int j = tid & 255, quarter = tid >> 8;   // 0..3
  __shared__ float hs[H];
  __shared__ float4 red[1024];             // 16 KB
  if (quarter == 0) hs[j] = 0.0f;
  float c = 0.0f, h = 0.0f;
  int nsteps = dir ? T : lengths[b];
  const uint4* pa = PAQ + (size_t)(quarter * 16) * 256 + j;
  const uint4* pb = PBQ + (size_t)(quarter * 16) * 256 + j;
  const float4* hs4 = reinterpret_cast<const float4*>(hs) + quarter * 16;
  __syncthreads();
  for (int s = 0; s < nsteps; ++s) {
    int t = dir ? (T - 1 - s) : s;
    float g0 = 0.f, g1 = 0.f, g2 = 0.f, g3 = 0.f;
#pragma unroll 4
    for (int k4 = 0; k4 < 16; ++k4) {
      uint4 a  = pa[(size_t)k4 * 256];
      uint4 bq = pb[(size_t)k4 * 256];
      float4 hv = hs4[k4];
      g0 = fmaf(hv.x, bf_lo(a.x), g0);  g1 = fmaf(hv.x, bf_hi(a.x), g1);
      g2 = fmaf(hv.x, bf_lo(bq.x), g2); g3 = fmaf(hv.x, bf_hi(bq.x), g3);
      g0 = fmaf(hv.y, bf_lo(a.y), g0);  g1 = fmaf(hv.y, bf_hi(a.y), g1);
      g2 = fmaf(hv.y, bf_lo(bq.y), g2); g3 = fmaf(hv.y, bf_hi(bq.y), g3);
      g0 = fmaf(hv.z, bf_lo(a.z), g0);  g1 = fmaf(hv.z, bf_hi(a.z), g1);
      g2 = fmaf(hv.z, bf_lo(bq.z), g2); g3 = fmaf(hv.z, bf_hi(bq.z), g3);
      g0 = fmaf(hv.w, bf_lo(a.w), g0);  g1 = fmaf(hv.w, bf_hi(a.w), g1);
      g2 = fmaf(hv.w, bf_lo(bq.w), g2); g3 = fmaf(hv.w, bf_hi(bq.w), g3);
    }
    red[tid] = make_float4(g0, g1, g2, g3);
    __syncthreads();
    if (quarter == 0) {
      float4 o1 = red[tid + 256];
      float4 o2 = red[tid + 512];
      float4 o3 = red[tid + 768];
      const float* xrow = xp + (size_t)(b * T + t) * G4;
      g0 += (o1.x + o2.x) + (o3.x + xrow[j]);
      g1 += (o1.y + o2.y) + (o3.y + xrow[j + 256]);
      g2 += (o1.z + o2.z) + (o3.z + xrow[j + 512]);
      g3 += (o1.w + o2.w) + (o3.w + xrow[j + 768]);
      float ig = sigmoidf(g0);
      float fg = sigmoidf(g1);
      float gg = tanhf_fast(g2);
      float og = sigmoidf(g3);
      c = fg * c + ig * gg;
      h = og * tanhf_fast(c);
      hs[j] = h;
      factsh[(size_t)(b * T + t) * D + dir * H + j] = (unsigned short)bf16rne(h);
    }
    __syncthreads();
  }
}

// ---------------- z halves -> bf16 ----------------
__global__ void k_buildz(const unsigned short* __restrict__ factsh, const float* __restrict__ v,
                         unsigned short* __restrict__ za, unsigned short* __restrict__ zb) {
  int bt = blockIdx.x;
  int b = bt / T;
  int d = threadIdx.x;  // 512
  float f = bfu(factsh[(size_t)bt * D + d]);
  float vv = v[(size_t)b * D + d];
  za[(size_t)bt * D + d] = (unsigned short)bf16rne(f * vv);
  zb[(size_t)bt * D + d] = (unsigned short)bf16rne(fabsf(f - vv));
}

// ---------------- score ----------------
__global__ void k_score(const float* __restrict__ att_h, const float* __restrict__ W2,
                        const float* __restrict__ b2, float* __restrict__ s) {
  int bt = blockIdx.x;
  int tid = threadIdx.x;  // 64
  float acc = 0.f;
  for (int e = tid; e < E; e += 64)
    acc += tanhf_fast(att_h[(size_t)bt * E + e]) * W2[e];
  for (int off = 32; off > 0; off >>= 1) acc += __shfl_down(acc, off);
  if (tid == 0) s[bt] = acc + b2[0];
}

// ---------------- masked softmax ----------------
__global__ void k_softmax(const float* __restrict__ s, const int* __restrict__ lengths,
                          float* __restrict__ a) {
  int b = blockIdx.x;
  int t = threadIdx.x;  // 128
  int len = lengths[b];
  __shared__ float wred[2];
  float val = -1e30f;
  if (t < T) val = (t < len) ? s[b * T + t] : -1e9f;
  float mx = val;
  for (int off = 32; off > 0; off >>= 1) mx = fmaxf(mx, __shfl_xor(mx, off));
  int wid = t >> 6, lane = t & 63;
  if (lane == 0) wred[wid] = mx;
  __syncthreads();
  mx = fmaxf(wred[0], wred[1]);
  __syncthreads();
  float e = (t < T && t < len) ? __expf(val - mx) : 0.0f;
  float sum = e;
  for (int off = 32; off > 0; off >>= 1) sum += __shfl_xor(sum, off);
  if (lane == 0) wred[wid] = sum;
  __syncthreads();
  float tot = wred[0] + wred[1];
  if (t < T) a[b * T + t] = e / tot;
}

// ---------------- zero helper ----------------
__global__ void k_zero(int* __restrict__ p, int n) {
  int i = blockIdx.x * blockDim.x + threadIdx.x;
  if (i < n) p[i] = 0;
}

// ---------------- attention GRU (round-14 verified) ----------------
#ifdef HAS_SDOT4
__global__ __launch_bounds__(1024) void k_gru(
    const unsigned* __restrict__ XRC, const uint4* __restrict__ UQ8,
    const unsigned* __restrict__ smax,
    const float* __restrict__ br, const float* __restrict__ bc,
    const float* __restrict__ att, const int* __restrict__ lengths,
    float* __restrict__ ep)
{
  int b = blockIdx.x;
  int tid = threadIdx.x;
  int j = tid & 511, half = tid >> 9;
  __shared__ int hqs[D / 4];       // packed i8 h, 512 B
  __shared__ int2 red2[1024];      // 8 KB
  if (tid < D / 4) hqs[tid] = 0;
  float hj = 0.0f;
  int len = lengths[b];
  float sAr = __uint_as_float(smax[0]) * (1.0f / 16129.0f);
  float sAc = __uint_as_float(smax[1]) * (1.0f / 16129.0f);
  float brj = br[j], bcj = bc[j];
  const uint4* up = UQ8 + (size_t)(half * 32) * 512 + j;
  __syncthreads();
  for (int t = 0; t < len; ++t) {
    float g = att[b * T + t];
    unsigned xq = XRC[(size_t)(b * T + t) * D + j];
    int ar = 0, ac = 0;
#pragma unroll 8
    for (int k8 = 0; k8 < 32; ++k8) {
      uint4 u = up[(size_t)k8 * 512];
      int h0 = hqs[(half * 32 + k8) * 2];
      int h1 = hqs[(half * 32 + k8) * 2 + 1];
      ar = __builtin_amdgcn_sdot4(h0, (int)u.x, ar, false);
      ac = __builtin_amdgcn_sdot4(h0, (int)u.y, ac, false);
      ar = __builtin_amdgcn_sdot4(h1, (int)u.z, ar, false);
      ac = __builtin_amdgcn_sdot4(h1, (int)u.w, ac, false);
    }
    red2[tid] = make_int2(ar, ac);
    __syncthreads();
    if (half == 0) {
      int2 o = red2[tid + 512];
      float racc = sAr * (float)(ar + o.x);
      float cacc = sAc * (float)(ac + o.y);
      float r  = sigmoidf(bf_lo(xq) + racc + brj);
      float hc = tanhf_fast(bf_hi(xq) + r * cacc + bcj);
      hj = g * hc + (1.f - g) * hj;
      ((signed char*)hqs)[j] = (signed char)__float2int_rn(hj * 127.0f);
    }
    __syncthreads();
  }
  if (half == 0) ep[(size_t)b * D + j] = hj;
}
#else
__global__ __launch_bounds__(1024) void k_gru(
    const unsigned* __restrict__ XRC, const uint4* __restrict__ UQ8,
    const unsigned* __restrict__ smax,
    const float* __restrict__ br, const float* __restrict__ bc,
    const float* __restrict__ att, const int* __restrict__ lengths,
    float* __restrict__ ep)
{
  int b = blockIdx.x;
  int tid = threadIdx.x;
  int j = tid & 511, half = tid >> 9;
  __shared__ float hs[D];
  __shared__ float2 red[1024];
  __shared__ float hsL;
  if (half == 0) hs[j] = 0.0f;
  if (tid == 0) hsL = 0.0f;
  float hj = 0.0f;
  int len = lengths[b];
  float s_r = __uint_as_float(smax[0]) * (1.0f / 127.0f);
  float s_c = __uint_as_float(smax[1]) * (1.0f / 127.0f);
  float brj = br[j], bcj = bc[j];
  const uint4* up = UQ8 + (size_t)(half * 32) * 512 + j;
  const float4* hs4 = reinterpret_cast<const float4*>(hs);
  __syncthreads();
  for (int t = 0; t < len; ++t) {
    float g = att[b * T + t];
    unsigned xq = XRC[(size_t)(b * T + t) * D + j];
    float qr = 0.f, qc = 0.f;
#pragma unroll 8
    for (int k8 = 0; k8 < 32; ++k8) {
      uint4 u = up[(size_t)k8 * 512];
      float4 h0 = hs4[(half * 32 + k8) * 2];
      float4 h1 = hs4[(half * 32 + k8) * 2 + 1];
      qr = fmaf(h0.x, UB0(u.x), qr); qc = fmaf(h0.x, UB1(u.x), qc);
      qr = fmaf(h0.y, UB2(u.x), qr); qc = fmaf(h0.y, UB3(u.x), qc);
      qr = fmaf(h0.z, UB0(u.y), qr); qc = fmaf(h0.z, UB1(u.y), qc);
      qr = fmaf(h0.w, UB2(u.y), qr); qc = fmaf(h0.w, UB3(u.y), qc);
      qr = fmaf(h1.x, UB0(u.z), qr); qc = fmaf(h1.x, UB1(u.z), qc);
      qr = fmaf(h1.y, UB2(u.z), qr); qc = fmaf(h1.y, UB3(u.z), qc);
      qr = fmaf(h1.z, UB0(u.w), qr); qc = fmaf(h1.z, UB1(u.w), qc);
      qr = fmaf(h1.w, UB2(u.w), qr); qc = fmaf(h1.w, UB3(u.w), qc);
    }
    red[tid] = make_float2(qr, qc);
    __syncthreads();
    if (half == 0) {
      float2 o = red[tid + 512];
      float hsum = hsL;
      float racc = s_r * (qr + o.x - 128.0f * hsum);
      float cacc = s_c * (qc + o.y - 128.0f * hsum);
      float r  = sigmoidf(bf_lo(xq) + racc + brj);
      float hc = tanhf_fast(bf_hi(xq) + r * cacc + bcj);
      hj = g * hc + (1.f - g) * hj;
      hs[j] = hj;
    }
    __syncthreads();
    if (tid < 64) {
      float4 a = hs4[2 * tid], bq = hs4[2 * tid + 1];
      float s4 = ((a.x + a.y) + (a.z + a.w)) + ((bq.x + bq.y) + (bq.z + bq.w));
      for (int off = 32; off > 0; off >>= 1) s4 += __shfl_down(s4, off);
      if (tid == 0) hsL = s4;
    }
  }
  if (half == 0) ep[(size_t)b * D + j] = hj;
}
#endif

// ---------------- hop projection ----------------
__global__ __launch_bounds__(512) void k_hop(
    const float* __restrict__ m_in, const float* __restrict__ ep,
    const float* __restrict__ q, const float* __restrict__ Whop,
    const float* __restrict__ bhop, float* __restrict__ m_out)
{
  int b = blockIdx.x, j = threadIdx.x;
  __shared__ float av[3 * D];
  av[j]         = m_in[(size_t)b * D + j];
  av[D + j]     = ep[(size_t)b * D + j];
  av[2 * D + j] = q[(size_t)b * D + j];
  __syncthreads();
  float acc = bhop[j];
#pragma unroll 4
  for (int k = 0; k < 3 * D; ++k)
    acc = fmaf(av[k], Whop[(size_t)k * D + j], acc);
  m_out[(size_t)b * D + j] = fmaxf(acc, 0.0f);
}

// ---------------- output ----------------
__global__ void k_out(const float* __restrict__ m, const float* __restrict__ q,
                      const float* __restrict__ Wo, const float* __restrict__ bo,
                      float* __restrict__ out)
{
  int b = blockIdx.x, tid = threadIdx.x;  // 256
  float acc = 0.f;
  for (int k = tid; k < D; k += 256)
    acc += m[(size_t)b * D + k] * Wo[k] + q[(size_t)b * D + k] * Wo[D + k];
  for (int off = 32; off > 0; off >>= 1) acc += __shfl_down(acc, off);
  __shared__ float red[4];
  int wid = tid >> 6, lane = tid & 63;
  if (lane == 0) red[wid] = acc;
  __syncthreads();
  if (tid == 0) {
    float tot = red[0] + red[1] + red[2] + red[3];
    out[b] = 1.0f / (1.0f + __expf(-(tot + bo[0])));
  }
}

extern "C" void kernel_launch(void* const* d_in, const int* in_sizes, int n_in,
                              void* d_out, int out_size, void* d_ws, size_t ws_size,
                              hipStream_t stream)
{
  const int*   tokens  = (const int*)d_in[0];
  const int*   lengths = (const int*)d_in[1];
  const float* emb     = (const float*)d_in[2];
  const float* Wx_f    = (const float*)d_in[3];
  const float* Wh_f    = (const float*)d_in[4];
  const float* b_f     = (const float*)d_in[5];
  const float* Wx_b    = (const float*)d_in[6];
  const float* Wh_b    = (const float*)d_in[7];
  const float* b_b     = (const float*)d_in[8];
  const float* W1      = (const float*)d_in[9];
  const float* b1      = (const float*)d_in[10];
  const float* W2      = (const float*)d_in[11];
  const float* b2      = (const float*)d_in[12];
  const float* Wr      = (const float*)d_in[13];
  const float* Ur      = (const float*)d_in[14];
  const float* br      = (const float*)d_in[15];
  const float* Wc      = (const float*)d_in[16];
  const float* Uc      = (const float*)d_in[17];
  const float* bc      = (const float*)d_in[18];
  const float* q       = (const float*)d_in[19];
  const float* W_hops  = (const float*)d_in[20];
  const float* b_hops  = (const float*)d_in[21];
  const float* Wo      = (const float*)d_in[22];
  const float* bo      = (const float*)d_in[23];
  float* ws = (float*)d_ws;

  // ---- workspace layout (identical to round 14) ----
  float* p = ws;
  unsigned short* xh = (unsigned short*)p;  p += (size_t)Mp * Ep / 2;
  float* xp_f   = p;  p += (size_t)BT * G4;                                 // later: xr | xc -> XRC
  float* xp_b   = p;  p += (size_t)BT * G4;                                 // later: za | zb
  unsigned short* factsh = (unsigned short*)p;  p += (size_t)Mp * D / 2;
  float* att_h  = p;  p += (size_t)BT * E;
  float* part0  = p;  p += (size_t)BT * E;
  float* scores = p;  p += BT;
  float* att    = p;  p += BT;
  float* m0     = p;  p += (size_t)B * D;
  float* m1     = p;  p += (size_t)B * D;
  float* epb    = p;  p += (size_t)B * D;
  unsigned* smax = (unsigned*)p;  p += 4;
  uint4* UQ8    = (uint4*)p;  p += (size_t)(D / 8) * D * 4;                 // 512KB int8 GRU weights
  uint4* PAQ_f  = (uint4*)p;  p += (size_t)(H / 4) * 256 * 4;
  uint4* PBQ_f  = (uint4*)p;  p += (size_t)(H / 4) * 256 * 4;
  uint4* PAQ_b  = (uint4*)p;  p += (size_t)(H / 4) * 256 * 4;
  uint4* PBQ_b  = (uint4*)p;  p += (size_t)(H / 4) * 256 * 4;
  unsigned short* WxT_f = (unsigned short*)p;  p += (size_t)G4 * Ep / 2;
  unsigned short* WxT_b = (unsigned short*)p;  p += (size_t)G4 * Ep / 2;
  unsigned short* WrT   = (unsigned short*)p;  p += (size_t)D * D / 2;
  unsigned short* WcT   = (unsigned short*)p;  p += (size_t)D * D / 2;
  unsigned short* W1T[4];
  for (int c = 0; c < 4; ++c) { W1T[c] = (unsigned short*)p; p += (size_t)Ep * D / 2; }
  float* xr = xp_f;
  float* xc = xp_f + (size_t)BT * D;
  unsigned* XRC = (unsigned*)xr;               // in-place bf16-pair pack over xr
  unsigned short* za = (unsigned short*)xp_b;
  unsigned short* zb = (unsigned short*)xp_b + (size_t)Mp * D;

  // 0) scales + pack weights (GRU int8; LSTM bf16; GEMM weights bf16^T)
  k_zero<<<1, 64, 0, stream>>>((int*)smax, 4);
  k_scales<<<D * D / 256, 256, 0, stream>>>(Ur, Uc, smax);
  k_pack_gru8<<<(D / 8) * D / 256, 256, 0, stream>>>(Ur, Uc, smax, UQ8);
  k_pack_lstm<<<(H / 4) * 256 / 256, 256, 0, stream>>>(Wh_f, PAQ_f, PBQ_f);
  k_pack_lstm<<<(H / 4) * 256 / 256, 256, 0, stream>>>(Wh_b, PAQ_b, PBQ_b);
  k_packT<<<G4 * Ep / 256, 256, 0, stream>>>(Wx_f, WxT_f, E, G4, G4, Ep);
  k_packT<<<G4 * Ep / 256, 256, 0, stream>>>(Wx_b, WxT_b, E, G4, G4, Ep);
  k_packT<<<D * D / 256, 256, 0, stream>>>(Wr, WrT, D, D, D, D);
  k_packT<<<D * D / 256, 256, 0, stream>>>(Wc, WcT, D, D, D, D);
  for (int c = 0; c < 4; ++c)
    k_packT<<<Ep * D / 256, 256, 0, stream>>>(W1 + (size_t)c * D * E, W1T[c], D, E, E, D);

  // 1) embed + input projections (MFMA)
  k_gather<<<BT, 256, 0, stream>>>(tokens, emb, xh);
  k_gemm_mfma<<<dim3(G4 / 64, Mp / 128), 256, 0, stream>>>(
      xh, WxT_f, Ep, Ep, nullptr, nullptr, 0, 0, b_f, nullptr, xp_f, G4, G4);
  k_gemm_mfma<<<dim3(G4 / 64, Mp / 128), 256, 0, stream>>>(
      xh, WxT_b, Ep, Ep, nullptr, nullptr, 0, 0, b_b, nullptr, xp_b, G4, G4);
  // 2) BiLSTM (bf16, 1024 threads / 4-way k-split)
  k_lstm<<<dim3(B, 2), 1024, 0, stream>>>(xp_f, xp_b, PAQ_f, PBQ_f, PAQ_b, PBQ_b, lengths, factsh);
  // 3) hop-invariant precomputes (MFMA); then pack xr/xc -> bf16 pairs in place
  k_gemm_mfma<<<dim3(D / 64, Mp / 128), 256, 0, stream>>>(
      factsh, WrT, D, D, nullptr, nullptr, 0, 0, nullptr, nullptr, xr, D, D);
  k_gemm_mfma<<<dim3(D / 64, Mp / 128), 256, 0, stream>>>(
      factsh, WcT, D, D, nullptr, nullptr, 0, 0, nullptr, nullptr, xc, D, D);
  k_packxrc<<<BT * D / 512, 512, 0, stream>>>(xr, xc, XRC);
  k_buildz<<<BT, 512, 0, stream>>>(factsh, q, za, zb);
  k_gemm_mfma<<<dim3(Ep / 64, Mp / 128), 256, 0, stream>>>(
      za, W1T[0], D, D, zb, W1T[2], D, D, b1, nullptr, part0, E, E);

  // 4) hops
  const float* m_in = q;
  float* mb[2] = {m0, m1};
  for (int i = 0; i < NH; ++i) {
    k_buildz<<<BT, 512, 0, stream>>>(factsh, m_in, za, zb);
    k_gemm_mfma<<<dim3(Ep / 64, Mp / 128), 256, 0, stream>>>(
        za, W1T[1], D, D, zb, W1T[3], D, D, nullptr, part0, att_h, E, E);
    k_score<<<BT, 64, 0, stream>>>(att_h, W2, b2, scores);
    k_softmax<<<B, 128, 0, stream>>>(scores, lengths, att);
    // GRU: per-batch streaming, signed-int8 dot4, no cross-block sync
    k_gru<<<B, 1024, 0, stream>>>(XRC, UQ8, smax, br, bc, att, lengths, epb);
    k_hop<<<B, 512, 0, stream>>>(m_in, epb, q,
                                 W_hops + (size_t)i * 3 * D * D, b_hops + (size_t)i * D,
                                 mb[i & 1]);
    m_in = mb[i & 1];
  }
  // 5) output
  k_out<<<B, 256, 0, stream>>>(m_in, q, Wo, bo, (float*)d_out);
}

// Round 18
// 2793.538 us; speedup vs baseline: 1.6453x; 1.0033x over previous
//
#include <hip/hip_runtime.h>

constexpr int B  = 64;
constexpr int T  = 121;
constexpr int E  = 300;
constexpr int Ep = 320;    // E padded to K-chunk multiple
constexpr int H  = 256;
constexpr int G4 = 1024;   // 4*H
constexpr int D  = 512;    // 2*H
constexpr int NH = 3;
constexpr int BT = B * T;  // 7744
constexpr int Mp = 7808;   // 61*128, M padded for 128-row tiles

using short8 = __attribute__((ext_vector_type(8))) short;
using f32x4  = __attribute__((ext_vector_type(4))) float;

__device__ __forceinline__ float sigmoidf(float x) { return 1.0f / (1.0f + __expf(-x)); }
__device__ __forceinline__ float tanhf_fast(float x) {
  float e = __expf(2.0f * x);
  return 1.0f - 2.0f / (e + 1.0f);
}
__device__ __forceinline__ unsigned bf16rne(float x) {
  unsigned u = __float_as_uint(x);
  return (u + 0x7fffu + ((u >> 16) & 1u)) >> 16;
}
__device__ __forceinline__ float bf_lo(unsigned u) { return __uint_as_float(u << 16); }
__device__ __forceinline__ float bf_hi(unsigned u) { return __uint_as_float(u & 0xffff0000u); }
__device__ __forceinline__ float bfu(unsigned short u) { return __uint_as_float(((unsigned)u) << 16); }

#if defined(__has_builtin)
#if __has_builtin(__builtin_amdgcn_sdot4)
#define HAS_SDOT4 1
#endif
#if __has_builtin(__builtin_amdgcn_cvt_f32_ubyte0)
#define HAS_UBYTE 1
#endif
#endif
#ifdef HAS_UBYTE
__device__ __forceinline__ float UB0(unsigned u) { return __builtin_amdgcn_cvt_f32_ubyte0(u); }
__device__ __forceinline__ float UB1(unsigned u) { return __builtin_amdgcn_cvt_f32_ubyte1(u); }
__device__ __forceinline__ float UB2(unsigned u) { return __builtin_amdgcn_cvt_f32_ubyte2(u); }
__device__ __forceinline__ float UB3(unsigned u) { return __builtin_amdgcn_cvt_f32_ubyte3(u); }
#else
__device__ __forceinline__ float UB0(unsigned u) { return (float)(u & 0xffu); }
__device__ __forceinline__ float UB1(unsigned u) { return (float)((u >> 8) & 0xffu); }
__device__ __forceinline__ float UB2(unsigned u) { return (float)((u >> 16) & 0xffu); }
__device__ __forceinline__ float UB3(unsigned u) { return (float)((u >> 24) & 0xffu); }
#endif

// ---------------- weight packing ----------------
// generic B^T bf16 pack with zero padding
__global__ void k_packT(const float* __restrict__ W, unsigned short* __restrict__ WT,
                        int Ksrc, int Nsrc, int stride, int Kpad) {
  int idx = blockIdx.x * 256 + threadIdx.x;
  int n = idx / Kpad, k = idx - n * Kpad;
  float v = (k < Ksrc && n < Nsrc) ? W[(size_t)k * stride + n] : 0.0f;
  WT[idx] = (unsigned short)bf16rne(v);
}

// pack xr/xc (f32) -> bf16 pair, IN PLACE over xr (no restrict: intentional alias)
__global__ void k_packxrc(const float* xr, const float* xc, unsigned* XRC) {
  size_t i = (size_t)blockIdx.x * 512 + threadIdx.x;
  float r = xr[i], c = xc[i];
  XRC[i] = bf16rne(r) | (bf16rne(c) << 16);
}

// absmax of Ur/Uc (uint-bit compare valid for non-negative floats)
__global__ void k_scales(const float* __restrict__ Ur, const float* __restrict__ Uc,
                         unsigned* __restrict__ smax) {
  int i = blockIdx.x * 256 + threadIdx.x;     // over D*D
  unsigned a = __float_as_uint(fabsf(Ur[i]));
  unsigned b = __float_as_uint(fabsf(Uc[i]));
  for (int off = 32; off > 0; off >>= 1) {
    a = max(a, (unsigned)__shfl_xor((int)a, off));
    b = max(b, (unsigned)__shfl_xor((int)b, off));
  }
  if ((threadIdx.x & 63) == 0) {
    atomicMax(&smax[0], a);
    atomicMax(&smax[1], b);
  }
}

// absmax of a single matrix (Wh, H*G4 elements) -> out[0]  (clone of verified k_scales)
__global__ void k_scalesW(const float* __restrict__ W, unsigned* __restrict__ out) {
  int i = blockIdx.x * 256 + threadIdx.x;     // over H*G4 = 262144
  unsigned a = __float_as_uint(fabsf(W[i]));
  for (int off = 32; off > 0; off >>= 1)
    a = max(a, (unsigned)__shfl_xor((int)a, off));
  if ((threadIdx.x & 63) == 0) atomicMax(&out[0], a);
}

// LSTM uint8 pack (round-13-verified unsigned zero-point scheme):
// PU8[k4*256 + j] = uint4; dword d packs gates (i,f,g,o) of k = 4*k4+d as bytes
// q = round(w*127/A) + 128 in [1,255].
__global__ void k_pack_lstm_u8(const float* __restrict__ Wh,
                               const unsigned* __restrict__ sW, uint4* __restrict__ PU8) {
  int idx = blockIdx.x * 256 + threadIdx.x;   // over (H/4)*256 = 16384
  int k4 = idx >> 8, j = idx & 255;
  float inv = 127.0f / __uint_as_float(sW[0]);
  unsigned dw[4];
#pragma unroll
  for (int d = 0; d < 4; ++d) {
    const float* row = Wh + (size_t)(4 * k4 + d) * G4;
    unsigned qi = (unsigned)(__float2int_rn(row[j]       * inv) + 128);
    unsigned qf = (unsigned)(__float2int_rn(row[j + 256] * inv) + 128);
    unsigned qg = (unsigned)(__float2int_rn(row[j + 512] * inv) + 128);
    unsigned qo = (unsigned)(__float2int_rn(row[j + 768] * inv) + 128);
    dw[d] = qi | (qf << 8) | (qg << 16) | (qo << 24);
  }
  PU8[idx] = make_uint4(dw[0], dw[1], dw[2], dw[3]);
}

#ifdef HAS_SDOT4
// signed 4-byte pack (GRU only — round-14 verified)
__device__ __forceinline__ unsigned pk4(float a, float b, float c, float d, float inv) {
  int qa = __float2int_rn(a * inv), qb = __float2int_rn(b * inv);
  int qc = __float2int_rn(c * inv), qd = __float2int_rn(d * inv);
  return (qa & 0xff) | ((qb & 0xff) << 8) | ((qc & 0xff) << 16) | ((qd & 0xff) << 24);
}
__global__ void k_pack_gru8(const float* __restrict__ Ur, const float* __restrict__ Uc,
                            const unsigned* __restrict__ smax, uint4* __restrict__ UQ8) {
  int idx = blockIdx.x * 256 + threadIdx.x;   // over (D/8)*D = 32768
  int k8 = idx >> 9, j = idx & 511;
  int k0 = k8 * 8;
  float invr = 127.0f / __uint_as_float(smax[0]);
  float invc = 127.0f / __uint_as_float(smax[1]);
  uint4 o;
  o.x = pk4(Ur[(size_t)(k0 + 0) * D + j], Ur[(size_t)(k0 + 1) * D + j],
            Ur[(size_t)(k0 + 2) * D + j], Ur[(size_t)(k0 + 3) * D + j], invr);
  o.y = pk4(Uc[(size_t)(k0 + 0) * D + j], Uc[(size_t)(k0 + 1) * D + j],
            Uc[(size_t)(k0 + 2) * D + j], Uc[(size_t)(k0 + 3) * D + j], invc);
  o.z = pk4(Ur[(size_t)(k0 + 4) * D + j], Ur[(size_t)(k0 + 5) * D + j],
            Ur[(size_t)(k0 + 6) * D + j], Ur[(size_t)(k0 + 7) * D + j], invr);
  o.w = pk4(Uc[(size_t)(k0 + 4) * D + j], Uc[(size_t)(k0 + 5) * D + j],
            Uc[(size_t)(k0 + 6) * D + j], Uc[(size_t)(k0 + 7) * D + j], invc);
  UQ8[idx] = o;
}
#else
// round-13 unsigned GRU pack
__global__ void k_pack_gru8(const float* __restrict__ Ur, const float* __restrict__ Uc,
                            const unsigned* __restrict__ smax, uint4* __restrict__ UQ8) {
  int idx = blockIdx.x * 256 + threadIdx.x;
  int k8 = idx >> 9, j = idx & 511;
  float invr = 127.0f / __uint_as_float(smax[0]);
  float invc = 127.0f / __uint_as_float(smax[1]);
  unsigned dw[4];
#pragma unroll
  for (int d = 0; d < 4; ++d) {
    int k0 = k8 * 8 + 2 * d;
    unsigned r0 = (unsigned)(__float2int_rn(Ur[(size_t)k0 * D + j] * invr) + 128);
    unsigned c0 = (unsigned)(__float2int_rn(Uc[(size_t)k0 * D + j] * invc) + 128);
    unsigned r1 = (unsigned)(__float2int_rn(Ur[(size_t)(k0 + 1) * D + j] * invr) + 128);
    unsigned c1 = (unsigned)(__float2int_rn(Uc[(size_t)(k0 + 1) * D + j] * invc) + 128);
    dw[d] = r0 | (c0 << 8) | (r1 << 16) | (c1 << 24);
  }
  UQ8[idx] = make_uint4(dw[0], dw[1], dw[2], dw[3]);
}
#endif

// ---------------- embedding gather -> bf16, K-padded ----------------
__global__ void k_gather(const int* __restrict__ tokens, const float* __restrict__ emb,
                         unsigned short* __restrict__ xh) {
  int bt = blockIdx.x;
  int tok = tokens[bt];
  const float* src = emb + (size_t)tok * E;
  unsigned short* dst = xh + (size_t)bt * Ep;
  for (int e = threadIdx.x; e < Ep; e += 256)
    dst[e] = (e < E) ? (unsigned short)bf16rne(src[e]) : (unsigned short)0;
}

// ---------------- bf16 MFMA GEMM (round-6 verified) ----------------
__global__ __launch_bounds__(256) void k_gemm_mfma(
    const unsigned short* __restrict__ A1, const unsigned short* __restrict__ B1, int K1, int lda1,
    const unsigned short* __restrict__ A2, const unsigned short* __restrict__ B2, int K2, int lda2,
    const float* __restrict__ bias, const float* __restrict__ Cin,
    float* __restrict__ C, int Nreal, int Cstride)
{
  __shared__ unsigned short As[128][40];
  __shared__ unsigned short Bs[64][40];
  int tid = threadIdx.x;
  int l = tid & 63, w = tid >> 6;
  int row0 = blockIdx.y * 128, col0 = blockIdx.x * 64;
  int lrow = l & 15, lk = (l >> 4) * 8, lq = (l >> 4) * 4;
  int ar = tid >> 1, asg = (tid & 1) * 16;
  int br = tid >> 2, bsg = (tid & 3) * 8;
  f32x4 acc[2][4] = {};
#pragma unroll 1
  for (int pass = 0; pass < 2; ++pass) {
    const unsigned short* A  = pass ? A2 : A1;
    const unsigned short* Bt = pass ? B2 : B1;
    int K   = pass ? K2 : K1;
    int lda = pass ? lda2 : lda1;
    if (K == 0) break;
    for (int k0 = 0; k0 < K; k0 += 32) {
      const uint4* ga = (const uint4*)(A + (size_t)(row0 + ar) * lda + k0 + asg);
      uint4 a0 = ga[0], a1 = ga[1];
      uint4 b0 = *(const uint4*)(Bt + (size_t)(col0 + br) * K + k0 + bsg);
      __syncthreads();
      *(uint4*)&As[ar][asg]     = a0;
      *(uint4*)&As[ar][asg + 8] = a1;
      *(uint4*)&Bs[br][bsg]     = b0;
      __syncthreads();
      short8 av[2], bv[4];
#pragma unroll
      for (int f = 0; f < 2; ++f)
        av[f] = *(const short8*)&As[w * 32 + f * 16 + lrow][lk];
#pragma unroll
      for (int fc = 0; fc < 4; ++fc)
        bv[fc] = *(const short8*)&Bs[fc * 16 + lrow][lk];
#pragma unroll
      for (int f = 0; f < 2; ++f)
#pragma unroll
        for (int fc = 0; fc < 4; ++fc)
          acc[f][fc] = __builtin_amdgcn_mfma_f32_16x16x32_bf16(av[f], bv[fc], acc[f][fc], 0, 0, 0);
    }
  }
#pragma unroll
  for (int f = 0; f < 2; ++f) {
#pragma unroll
    for (int fc = 0; fc < 4; ++fc) {
      int c = col0 + fc * 16 + lrow;
      if (c < Nreal) {
        float bb = bias ? bias[c] : 0.0f;
#pragma unroll
        for (int i = 0; i < 4; ++i) {
          int r = row0 + w * 32 + f * 16 + lq + i;
          if (r < BT) {
            float v = acc[f][fc][i] + bb;
            if (Cin) v += Cin[(size_t)r * Cstride + c];
            C[(size_t)r * Cstride + c] = v;
          }
        }
      }
    }
  }
}

// ---------------- BiLSTM scan: uint8 weights + fma decode (round-13-verified scheme),
// 1024 thr / 4-way k-split (round-17-verified shell). h stays fp32 in LDS.
// Zero-point: gate = s*(q - 128*sum(h)); sum(h) by wave 0 (round-13-verified ordering).
__global__ __launch_bounds__(1024) void k_lstm(
    const float* __restrict__ xp_f, const float* __restrict__ xp_b,
    const uint4* __restrict__ PU8_f, const uint4* __restrict__ PU8_b,
    const unsigned* __restrict__ smax,   // [2]=Wh_f absmax, [3]=Wh_b absmax
    const int* __restrict__ lengths, unsigned short* __restrict__ factsh)
{
  int b = blockIdx.x;
  int dir = blockIdx.y;
  const float* xp = dir ? xp_b : xp_f;
  const uint4* PU = dir ? PU8_b : PU8_f;
  int tid = threadIdx.x;
  int j = tid & 255, quarter = tid >> 8;   // 0..3
  __shared__ float hs[H];
  __shared__ float4 red[1024];             // 16 KB
  __shared__ float hsL;
  if (quarter == 0) hs[j] = 0.0f;
  if (tid == 0) hsL = 0.0f;
  float c = 0.0f, h = 0.0f;
  int nsteps = dir ? T : lengths[b];
  float sW = __uint_as_float(smax[2 + dir]) * (1.0f / 127.0f);
  const uint4* pu = PU + (size_t)(quarter * 16) * 256 + j;
  const float4* hs4q = reinterpret_cast<const float4*>(hs) + quarter * 16;
  const float4* hs4  = reinterpret_cast<const float4*>(hs);
  __syncthreads();
  for (int s = 0; s < nsteps; ++s) {
    int t = dir ? (T - 1 - s) : s;
    float g0 = 0.f, g1 = 0.f, g2 = 0.f, g3 = 0.f;
#pragma unroll 4
    for (int k4 = 0; k4 < 16; ++k4) {
      uint4 u = pu[(size_t)k4 * 256];
      float4 hv = hs4q[k4];
      g0 = fmaf(hv.x, UB0(u.x), g0); g1 = fmaf(hv.x, UB1(u.x), g1);
      g2 = fmaf(hv.x, UB2(u.x), g2); g3 = fmaf(hv.x, UB3(u.x), g3);
      g0 = fmaf(hv.y, UB0(u.y), g0); g1 = fmaf(hv.y, UB1(u.y), g1);
      g2 = fmaf(hv.y, UB2(u.y), g2); g3 = fmaf(hv.y, UB3(u.y), g3);
      g0 = fmaf(hv.z, UB0(u.z), g0); g1 = fmaf(hv.z, UB1(u.z), g1);
      g2 = fmaf(hv.z, UB2(u.z), g2); g3 = fmaf(hv.z, UB3(u.z), g3);
      g0 = fmaf(hv.w, UB0(u.w), g0); g1 = fmaf(hv.w, UB1(u.w), g1);
      g2 = fmaf(hv.w, UB2(u.w), g2); g3 = fmaf(hv.w, UB3(u.w), g3);
    }
    red[tid] = make_float4(g0, g1, g2, g3);
    __syncthreads();
    if (quarter == 0) {
      float4 o1 = red[tid + 256];
      float4 o2 = red[tid + 512];
      float4 o3 = red[tid + 768];
      float hsum = hsL;
      const float* xrow = xp + (size_t)(b * T + t) * G4;
      float q0 = g0 + (o1.x + o2.x) + o3.x;
      float q1 = g1 + (o1.y + o2.y) + o3.y;
      float q2 = g2 + (o1.z + o2.z) + o3.z;
      float q3 = g3 + (o1.w + o2.w) + o3.w;
      float a0 = xrow[j]       + sW * (q0 - 128.0f * hsum);
      float a1 = xrow[j + 256] + sW * (q1 - 128.0f * hsum);
      float a2 = xrow[j + 512] + sW * (q2 - 128.0f * hsum);
      float a3 = xrow[j + 768] + sW * (q3 - 128.0f * hsum);
      float ig = sigmoidf(a0);
      float fg = sigmoidf(a1);
      float gg = tanhf_fast(a2);
      float og = sigmoidf(a3);
      c = fg * c + ig * gg;
      h = og * tanhf_fast(c);
      hs[j] = h;
      factsh[(size_t)(b * T + t) * D + dir * H + j] = (unsigned short)bf16rne(h);
    }
    __syncthreads();
    // wave 0: sum of new h for next step's zero-point correction (round-13 ordering)
    if (tid < 64) {
      float4 a = hs4[tid];
      float s4 = (a.x + a.y) + (a.z + a.w);
      for (int off = 32; off > 0; off >>= 1) s4 += __shfl_down(s4, off);
      if (tid == 0) hsL = s4;
    }
  }
}

// ---------------- z halves -> bf16 ----------------
__global__ void k_buildz(const unsigned short* __restrict__ factsh, const float* __restrict__ v,
                         unsigned short* __restrict__ za, unsigned short* __restrict__ zb) {
  int bt = blockIdx.x;
  int b = bt / T;
  int d = threadIdx.x;  // 512
  float f = bfu(factsh[(size_t)bt * D + d]);
  float vv = v[(size_t)b * D + d];
  za[(size_t)bt * D + d] = (unsigned short)bf16rne(f * vv);
  zb[(size_t)bt * D + d] = (unsigned short)bf16rne(fabsf(f - vv));
}

// ---------------- score ----------------
__global__ void k_score(const float* __restrict__ att_h, const float* __restrict__ W2,
                        const float* __restrict__ b2, float* __restrict__ s) {
  int bt = blockIdx.x;
  int tid = threadIdx.x;  // 64
  float acc = 0.f;
  for (int e = tid; e < E; e += 64)
    acc += tanhf_fast(att_h[(size_t)bt * E + e]) * W2[e];
  for (int off = 32; off > 0; off >>= 1) acc += __shfl_down(acc, off);
  if (tid == 0) s[bt] = acc + b2[0];
}

// ---------------- masked softmax ----------------
__global__ void k_softmax(const float* __restrict__ s, const int* __restrict__ lengths,
                          float* __restrict__ a) {
  int b = blockIdx.x;
  int t = threadIdx.x;  // 128
  int len = lengths[b];
  __shared__ float wred[2];
  float val = -1e30f;
  if (t < T) val = (t < len) ? s[b * T + t] : -1e9f;
  float mx = val;
  for (int off = 32; off > 0; off >>= 1) mx = fmaxf(mx, __shfl_xor(mx, off));
  int wid = t >> 6, lane = t & 63;
  if (lane == 0) wred[wid] = mx;
  __syncthreads();
  mx = fmaxf(wred[0], wred[1]);
  __syncthreads();
  float e = (t < T && t < len) ? __expf(val - mx) : 0.0f;
  float sum = e;
  for (int off = 32; off > 0; off >>= 1) sum += __shfl_xor(sum, off);
  if (lane == 0) wred[wid] = sum;
  __syncthreads();
  float tot = wred[0] + wred[1];
  if (t < T) a[b * T + t] = e / tot;
}

// ---------------- zero helper ----------------
__global__ void k_zero(int* __restrict__ p, int n) {
  int i = blockIdx.x * blockDim.x + threadIdx.x;
  if (i < n) p[i] = 0;
}

// ---------------- attention GRU (round-14 verified) ----------------
#ifdef HAS_SDOT4
__global__ __launch_bounds__(1024) void k_gru(
    const unsigned* __restrict__ XRC, const uint4* __restrict__ UQ8,
    const unsigned* __restrict__ smax,
    const float* __restrict__ br, const float* __restrict__ bc,
    const float* __restrict__ att, const int* __restrict__ lengths,
    float* __restrict__ ep)
{
  int b = blockIdx.x;
  int tid = threadIdx.x;
  int j = tid & 511, half = tid >> 9;
  __shared__ int hqs[D / 4];       // packed i8 h, 512 B
  __shared__ int2 red2[1024];      // 8 KB
  if (tid < D / 4) hqs[tid] = 0;
  float hj = 0.0f;
  int len = lengths[b];
  float sAr = __uint_as_float(smax[0]) * (1.0f / 16129.0f);
  float sAc = __uint_as_float(smax[1]) * (1.0f / 16129.0f);
  float brj = br[j], bcj = bc[j];
  const uint4* up = UQ8 + (size_t)(half * 32) * 512 + j;
  __syncthreads();
  for (int t = 0; t < len; ++t) {
    float g = att[b * T + t];
    unsigned xq = XRC[(size_t)(b * T + t) * D + j];
    int ar = 0, ac = 0;
#pragma unroll 8
    for (int k8 = 0; k8 < 32; ++k8) {
      uint4 u = up[(size_t)k8 * 512];
      int h0 = hqs[(half * 32 + k8) * 2];
      int h1 = hqs[(half * 32 + k8) * 2 + 1];
      ar = __builtin_amdgcn_sdot4(h0, (int)u.x, ar, false);
      ac = __builtin_amdgcn_sdot4(h0, (int)u.y, ac, false);
      ar = __builtin_amdgcn_sdot4(h1, (int)u.z, ar, false);
      ac = __builtin_amdgcn_sdot4(h1, (int)u.w, ac, false);
    }
    red2[tid] = make_int2(ar, ac);
    __syncthreads();
    if (half == 0) {
      int2 o = red2[tid + 512];
      float racc = sAr * (float)(ar + o.x);
      float cacc = sAc * (float)(ac + o.y);
      float r  = sigmoidf(bf_lo(xq) + racc + brj);
      float hc = tanhf_fast(bf_hi(xq) + r * cacc + bcj);
      hj = g * hc + (1.f - g) * hj;
      ((signed char*)hqs)[j] = (signed char)__float2int_rn(hj * 127.0f);
    }
    __syncthreads();
  }
  if (half == 0) ep[(size_t)b * D + j] = hj;
}
#else
__global__ __launch_bounds__(1024) void k_gru(
    const unsigned* __restrict__ XRC, const uint4* __restrict__ UQ8,
    const unsigned* __restrict__ smax,
    const float* __restrict__ br, const float* __restrict__ bc,
    const float* __restrict__ att, const int* __restrict__ lengths,
    float* __restrict__ ep)
{
  int b = blockIdx.x;
  int tid = threadIdx.x;
  int j = tid & 511, half = tid >> 9;
  __shared__ float hs[D];
  __shared__ float2 red[1024];
  __shared__ float hsL;
  if (half == 0) hs[j] = 0.0f;
  if (tid == 0) hsL = 0.0f;
  float hj = 0.0f;
  int len = lengths[b];
  float s_r = __uint_as_float(smax[0]) * (1.0f / 127.0f);
  float s_c = __uint_as_float(smax[1]) * (1.0f / 127.0f);
  float brj = br[j], bcj = bc[j];
  const uint4* up = UQ8 + (size_t)(half * 32) * 512 + j;
  const float4* hs4 = reinterpret_cast<const float4*>(hs);
  __syncthreads();
  for (int t = 0; t < len; ++t) {
    float g = att[b * T + t];
    unsigned xq = XRC[(size_t)(b * T + t) * D + j];
    float qr = 0.f, qc = 0.f;
#pragma unroll 8
    for (int k8 = 0; k8 < 32; ++k8) {
      uint4 u = up[(size_t)k8 * 512];
      float4 h0 = hs4[(half * 32 + k8) * 2];
      float4 h1 = hs4[(half * 32 + k8) * 2 + 1];
      qr = fmaf(h0.x, UB0(u.x), qr); qc = fmaf(h0.x, UB1(u.x), qc);
      qr = fmaf(h0.y, UB2(u.x), qr); qc = fmaf(h0.y, UB3(u.x), qc);
      qr = fmaf(h0.z, UB0(u.y), qr); qc = fmaf(h0.z, UB1(u.y), qc);
      qr = fmaf(h0.w, UB2(u.y), qr); qc = fmaf(h0.w, UB3(u.y), qc);
      qr = fmaf(h1.x, UB0(u.z), qr); qc = fmaf(h1.x, UB1(u.z), qc);
      qr = fmaf(h1.y, UB2(u.z), qr); qc = fmaf(h1.y, UB3(u.z), qc);
      qr = fmaf(h1.z, UB0(u.w), qr); qc = fmaf(h1.z, UB1(u.w), qc);
      qr = fmaf(h1.w, UB2(u.w), qr); qc = fmaf(h1.w, UB3(u.w), qc);
    }
    red[tid] = make_float2(qr, qc);
    __syncthreads();
    if (half == 0) {
      float2 o = red[tid + 512];
      float hsum = hsL;
      float racc = s_r * (qr + o.x - 128.0f * hsum);
      float cacc = s_c * (qc + o.y - 128.0f * hsum);
      float r  = sigmoidf(bf_lo(xq) + racc + brj);
      float hc = tanhf_fast(bf_hi(xq) + r * cacc + bcj);
      hj = g * hc + (1.f - g) * hj;
      hs[j] = hj;
    }
    __syncthreads();
    if (tid < 64) {
      float4 a = hs4[2 * tid], bq = hs4[2 * tid + 1];
      float s4 = ((a.x + a.y) + (a.z + a.w)) + ((bq.x + bq.y) + (bq.z + bq.w));
      for (int off = 32; off > 0; off >>= 1) s4 += __shfl_down(s4, off);
      if (tid == 0) hsL = s4;
    }
  }
  if (half == 0) ep[(size_t)b * D + j] = hj;
}
#endif

// ---------------- hop projection ----------------
__global__ __launch_bounds__(512) void k_hop(
    const float* __restrict__ m_in, const float* __restrict__ ep,
    const float* __restrict__ q, const float* __restrict__ Whop,
    const float* __restrict__ bhop, float* __restrict__ m_out)
{
  int b = blockIdx.x, j = threadIdx.x;
  __shared__ float av[3 * D];
  av[j]         = m_in[(size_t)b * D + j];
  av[D + j]     = ep[(size_t)b * D + j];
  av[2 * D + j] = q[(size_t)b * D + j];
  __syncthreads();
  float acc = bhop[j];
#pragma unroll 4
  for (int k = 0; k < 3 * D; ++k)
    acc = fmaf(av[k], Whop[(size_t)k * D + j], acc);
  m_out[(size_t)b * D + j] = fmaxf(acc, 0.0f);
}

// ---------------- output ----------------
__global__ void k_out(const float* __restrict__ m, const float* __restrict__ q,
                      const float* __restrict__ Wo, const float* __restrict__ bo,
                      float* __restrict__ out)
{
  int b = blockIdx.x, tid = threadIdx.x;  // 256
  float acc = 0.f;
  for (int k = tid; k < D; k += 256)
    acc += m[(size_t)b * D + k] * Wo[k] + q[(size_t)b * D + k] * Wo[D + k];
  for (int off = 32; off > 0; off >>= 1) acc += __shfl_down(acc, off);
  __shared__ float red[4];
  int wid = tid >> 6, lane = tid & 63;
  if (lane == 0) red[wid] = acc;
  __syncthreads();
  if (tid == 0) {
    float tot = red[0] + red[1] + red[2] + red[3];
    out[b] = 1.0f / (1.0f + __expf(-(tot + bo[0])));
  }
}

extern "C" void kernel_launch(void* const* d_in, const int* in_sizes, int n_in,
                              void* d_out, int out_size, void* d_ws, size_t ws_size,
                              hipStream_t stream)
{
  const int*   tokens  = (const int*)d_in[0];
  const int*   lengths = (const int*)d_in[1];
  const float* emb     = (const float*)d_in[2];
  const float* Wx_f    = (const float*)d_in[3];
  const float* Wh_f    = (const float*)d_in[4];
  const float* b_f     = (const float*)d_in[5];
  const float* Wx_b    = (const float*)d_in[6];
  const float* Wh_b    = (const float*)d_in[7];
  const float* b_b     = (const float*)d_in[8];
  const float* W1      = (const float*)d_in[9];
  const float* b1      = (const float*)d_in[10];
  const float* W2      = (const float*)d_in[11];
  const float* b2      = (const float*)d_in[12];
  const float* Wr      = (const float*)d_in[13];
  const float* Ur      = (const float*)d_in[14];
  const float* br      = (const float*)d_in[15];
  const float* Wc      = (const float*)d_in[16];
  const float* Uc      = (const float*)d_in[17];
  const float* bc      = (const float*)d_in[18];
  const float* q       = (const float*)d_in[19];
  const float* W_hops  = (const float*)d_in[20];
  const float* b_hops  = (const float*)d_in[21];
  const float* Wo      = (const float*)d_in[22];
  const float* bo      = (const float*)d_in[23];
  float* ws = (float*)d_ws;

  // ---- workspace layout (round-14 base; PU8 buffers reuse PAQ/PBQ slots) ----
  float* p = ws;
  unsigned short* xh = (unsigned short*)p;  p += (size_t)Mp * Ep / 2;
  float* xp_f   = p;  p += (size_t)BT * G4;                                 // later: xr | xc -> XRC
  float* xp_b   = p;  p += (size_t)BT * G4;                                 // later: za | zb
  unsigned short* factsh = (unsigned short*)p;  p += (size_t)Mp * D / 2;
  float* att_h  = p;  p += (size_t)BT * E;
  float* part0  = p;  p += (size_t)BT * E;
  float* scores = p;  p += BT;
  float* att    = p;  p += BT;
  float* m0     = p;  p += (size_t)B * D;
  float* m1     = p;  p += (size_t)B * D;
  float* epb    = p;  p += (size_t)B * D;
  unsigned* smax = (unsigned*)p;  p += 4;                                   // [0,1]=GRU, [2]=Wh_f, [3]=Wh_b
  uint4* UQ8    = (uint4*)p;  p += (size_t)(D / 8) * D * 4;                 // 512KB int8 GRU weights
  uint4* PU8_f  = (uint4*)p;  p += (size_t)(H / 4) * 256 * 4;               // 256KB uint8 LSTM weights
  uint4* PU8_b  = (uint4*)p;  p += (size_t)(H / 4) * 256 * 4;
  uint4* unused0 = (uint4*)p;  p += (size_t)(H / 4) * 256 * 4;              // keep layout stable
  uint4* unused1 = (uint4*)p;  p += (size_t)(H / 4) * 256 * 4;
  (void)unused0; (void)unused1;
  unsigned short* WxT_f = (unsigned short*)p;  p += (size_t)G4 * Ep / 2;
  unsigned short* WxT_b = (unsigned short*)p;  p += (size_t)G4 * Ep / 2;
  unsigned short* WrT   = (unsigned short*)p;  p += (size_t)D * D / 2;
  unsigned short* WcT   = (unsigned short*)p;  p += (size_t)D * D / 2;
  unsigned short* W1T[4];
  for (int c = 0; c < 4; ++c) { W1T[c] = (unsigned short*)p; p += (size_t)Ep * D / 2; }
  float* xr = xp_f;
  float* xc = xp_f + (size_t)BT * D;
  unsigned* XRC = (unsigned*)xr;               // in-place bf16-pair pack over xr
  unsigned short* za = (unsigned short*)xp_b;
  unsigned short* zb = (unsigned short*)xp_b + (size_t)Mp * D;

  // 0) scales + pack weights (GRU int8 dot4; LSTM uint8 fma; GEMM weights bf16^T)
  k_zero<<<1, 64, 0, stream>>>((int*)smax, 4);
  k_scales<<<D * D / 256, 256, 0, stream>>>(Ur, Uc, smax);
  k_scalesW<<<H * G4 / 256, 256, 0, stream>>>(Wh_f, smax + 2);
  k_scalesW<<<H * G4 / 256, 256, 0, stream>>>(Wh_b, smax + 3);
  k_pack_gru8<<<(D / 8) * D / 256, 256, 0, stream>>>(Ur, Uc, smax, UQ8);
  k_pack_lstm_u8<<<(H / 4) * 256 / 256, 256, 0, stream>>>(Wh_f, smax + 2, PU8_f);
  k_pack_lstm_u8<<<(H / 4) * 256 / 256, 256, 0, stream>>>(Wh_b, smax + 3, PU8_b);
  k_packT<<<G4 * Ep / 256, 256, 0, stream>>>(Wx_f, WxT_f, E, G4, G4, Ep);
  k_packT<<<G4 * Ep / 256, 256, 0, stream>>>(Wx_b, WxT_b, E, G4, G4, Ep);
  k_packT<<<D * D / 256, 256, 0, stream>>>(Wr, WrT, D, D, D, D);
  k_packT<<<D * D / 256, 256, 0, stream>>>(Wc, WcT, D, D, D, D);
  for (int c = 0; c < 4; ++c)
    k_packT<<<Ep * D / 256, 256, 0, stream>>>(W1 + (size_t)c * D * E, W1T[c], D, E, E, D);

  // 1) embed + input projections (MFMA)
  k_gather<<<BT, 256, 0, stream>>>(tokens, emb, xh);
  k_gemm_mfma<<<dim3(G4 / 64, Mp / 128), 256, 0, stream>>>(
      xh, WxT_f, Ep, Ep, nullptr, nullptr, 0, 0, b_f, nullptr, xp_f, G4, G4);
  k_gemm_mfma<<<dim3(G4 / 64, Mp / 128), 256, 0, stream>>>(
      xh, WxT_b, Ep, Ep, nullptr, nullptr, 0, 0, b_b, nullptr, xp_b, G4, G4);
  // 2) BiLSTM (uint8 fma, 1024 threads / 4-way k-split)
  k_lstm<<<dim3(B, 2), 1024, 0, stream>>>(xp_f, xp_b, PU8_f, PU8_b, smax, lengths, factsh);
  // 3) hop-invariant precomputes (MFMA); then pack xr/xc -> bf16 pairs in place
  k_gemm_mfma<<<dim3(D / 64, Mp / 128), 256, 0, stream>>>(
      factsh, WrT, D, D, nullptr, nullptr, 0, 0, nullptr, nullptr, xr, D, D);
  k_gemm_mfma<<<dim3(D / 64, Mp / 128), 256, 0, stream>>>(
      factsh, WcT, D, D, nullptr, nullptr, 0, 0, nullptr, nullptr, xc, D, D);
  k_packxrc<<<BT * D / 512, 512, 0, stream>>>(xr, xc, XRC);
  k_buildz<<<BT, 512, 0, stream>>>(factsh, q, za, zb);
  k_gemm_mfma<<<dim3(Ep / 64, Mp / 128), 256, 0, stream>>>(
      za, W1T[0], D, D, zb, W1T[2], D, D, b1, nullptr, part0, E, E);

  // 4) hops
  const float* m_in = q;
  float* mb[2] = {m0, m1};
  for (int i = 0; i < NH; ++i) {
    k_buildz<<<BT, 512, 0, stream>>>(factsh, m_in, za, zb);
    k_gemm_mfma<<<dim3(Ep / 64, Mp / 128), 256, 0, stream>>>(
        za, W1T[1], D, D, zb, W1T[3], D, D, nullptr, part0, att_h, E, E);
    k_score<<<BT, 64, 0, stream>>>(att_h, W2, b2, scores);
    k_softmax<<<B, 128, 0, stream>>>(scores, lengths, att);
    // GRU: per-batch streaming, signed-int8 dot4, no cross-block sync
    k_gru<<<B, 1024, 0, stream>>>(XRC, UQ8, smax, br, bc, att, lengths, epb);
    k_hop<<<B, 512, 0, stream>>>(m_in, epb, q,
                                 W_hops + (size_t)i * 3 * D * D, b_hops + (size_t)i * D,
                                 mb[i & 1]);
    m_in = mb[i & 1];
  }
  // 5) output
  k_out<<<B, 256, 0, stream>>>(m_in, q, Wo, bo, (float*)d_out);
}